// Round 6
// baseline (1457.171 us; speedup 1.0000x reference)
//
#include <hip/hip_runtime.h>
#include <stdint.h>

// LinearAttention (gated delta rule), S=2048, HID=2048, H=16, DK=64, DV=128, conv K=4.
// Established r1-r5: inputs f32; OUTPUT IS F32 (identical absmax across MFMA/VALU builds
// + threshold has no bf16 floor -> harness reads d_out as f32; r3-r5 wrote bf16 = garbage).
// r6: r4's MFMA pipeline + f32 final store.
//
// Pipeline: proj_ab -> gemm(QKV) -> conv+SiLU+l2norm -> gemm(Z) -> delta-rule scan
//           -> RMSNorm*SiLU(z) gate -> gemm(out, f32) -> d_out
//
// ws layout (peak 24 MiB + 260 KiB):
//   [0,16M)   mixed bf16 2048x4096 (gemm1->conv); after conv: zbuf @0 (8M), core @8M (8M)
//   [16M,20M) qbuf bf16; [20M,24M) kbuf bf16; after scan: gated @16M (8M)
//   [24M..)   eg f32 (128K) | beta f32 (128K) | dtype flag
// d_out (16 MiB f32): first 8 MiB doubles as vbuf bf16 scratch (conv->scan), then the
// final gemm overwrites every element as f32.

#define SEQ 2048
#define HIDDEN 2048
#define NH 16
#define DKv 64
#define DVv 128
#define KEY_DIM 1024
#define VAL_DIM 2048
#define CONV_DIM 4096

typedef __bf16 bf16;
typedef unsigned short u16;
typedef __attribute__((ext_vector_type(8))) __bf16 bf16x8;
typedef __attribute__((ext_vector_type(4))) float f32x4;

__device__ __forceinline__ float b2f(u16 u) {
  union { unsigned int i; float f; } c; c.i = ((unsigned int)u) << 16; return c.f;
}
__device__ __forceinline__ float sigmoidf_(float x) { return 1.0f / (1.0f + __expf(-x)); }

// ---------------------------------------------------------------- dtype detector
// (kept for robustness; r3-r5 established flag=1 i.e. f32 inputs)
__global__ void detect_dtype(const u16* __restrict__ p, unsigned* __restrict__ flag) {
  int lane = threadIdx.x;  // 64 threads
  int cnt = 0;
  for (int w = lane; w < 2048; w += 64) {
    unsigned e = (p[2 * w] >> 7) & 0xFF;
    if (e < 64) cnt++;
  }
  cnt += __shfl_xor(cnt, 1);  cnt += __shfl_xor(cnt, 2);  cnt += __shfl_xor(cnt, 4);
  cnt += __shfl_xor(cnt, 8);  cnt += __shfl_xor(cnt, 16); cnt += __shfl_xor(cnt, 32);
  if (lane == 0) *flag = (cnt > 64) ? 1u : 0u;   // 1 = inputs are f32
}

// ---------------------------------------------------------------- GEMM (NT)
// C[M,N] = A[M,K] @ B[N,K]^T, f32 accum; C dtype = F32OUT ? f32 : bf16.
// useA/useB=1 -> honor flag (f32 cvt-stage via ds_write_b128, or bf16 global_load_lds);
// 0 -> always-bf16 internal buffer. 128x128 tile, BK=32, 4 waves, mfma 16x16x32_bf16.
template<bool F32OUT>
__global__ __launch_bounds__(256, 2)
void gemm_nt(const void* __restrict__ Araw, const void* __restrict__ Braw,
             void* __restrict__ Cv, int N, int K,
             const unsigned* __restrict__ flagp, int useA, int useB) {
  __shared__ __align__(16) bf16 As[128 * 32];
  __shared__ __align__(16) bf16 Bs[128 * 32];
  const bool f32g = (*flagp != 0);
  const bool fA = useA && f32g;
  const bool fB = useB && f32g;
  const int tid  = threadIdx.x;
  const int lane = tid & 63;
  const int wv   = tid >> 6;
  const int wm   = (wv & 1) << 6;
  const int wn   = (wv >> 1) << 6;
  const long bm  = (long)blockIdx.y * 128;
  const long bn  = (long)blockIdx.x * 128;

  f32x4 acc[4][4] = {};

  for (int k0 = 0; k0 < K; k0 += 32) {
#pragma unroll
    for (int it = 0; it < 2; ++it) {
      int e   = (it * 256 + tid) * 8;   // bf16 element index in the 128x32 tile
      int row = e >> 5;                 // 0..127
      int col = e & 31;                 // {0,8,16,24}
      long offA = (bm + row) * (long)K + (k0 + col);
      long offB = (bn + row) * (long)K + (k0 + col);
      if (fA) {
        const float* g = (const float*)Araw + offA;
        f32x4 u0 = *(const f32x4*)g, u1 = *(const f32x4*)(g + 4);
        bf16x8 bv;
#pragma unroll
        for (int j = 0; j < 4; ++j) { bv[j] = (bf16)u0[j]; bv[4 + j] = (bf16)u1[j]; }
        *(bf16x8*)&As[e] = bv;          // ds_write_b128
      } else {
        const bf16* g = (const bf16*)Araw + offA;
        __builtin_amdgcn_global_load_lds(
            (__attribute__((address_space(1))) const void*)g,
            (__attribute__((address_space(3))) void*)&As[e], 16, 0, 0);
      }
      if (fB) {
        const float* g = (const float*)Braw + offB;
        f32x4 u0 = *(const f32x4*)g, u1 = *(const f32x4*)(g + 4);
        bf16x8 bv;
#pragma unroll
        for (int j = 0; j < 4; ++j) { bv[j] = (bf16)u0[j]; bv[4 + j] = (bf16)u1[j]; }
        *(bf16x8*)&Bs[e] = bv;
      } else {
        const bf16* g = (const bf16*)Braw + offB;
        __builtin_amdgcn_global_load_lds(
            (__attribute__((address_space(1))) const void*)g,
            (__attribute__((address_space(3))) void*)&Bs[e], 16, 0, 0);
      }
    }
    __syncthreads();  // drains vmcnt (DMA) + lgkmcnt (ds_write)

    const bf16x8* As8 = (const bf16x8*)As;
    const bf16x8* Bs8 = (const bf16x8*)Bs;
    const int r = lane & 15, q = lane >> 4;
    bf16x8 af[4], bfr[4];
#pragma unroll
    for (int i = 0; i < 4; ++i) af[i]  = As8[(wm + i * 16 + r) * 4 + q];
#pragma unroll
    for (int j = 0; j < 4; ++j) bfr[j] = Bs8[(wn + j * 16 + r) * 4 + q];
#pragma unroll
    for (int i = 0; i < 4; ++i)
#pragma unroll
      for (int j = 0; j < 4; ++j)
        acc[i][j] = __builtin_amdgcn_mfma_f32_16x16x32_bf16(af[i], bfr[j], acc[i][j], 0, 0, 0);
    __syncthreads();
  }

  // C/D layout: col = lane&15, row = (lane>>4)*4 + reg  [HW-verified m89/m91]
  const int r = lane & 15, q = lane >> 4;
#pragma unroll
  for (int i = 0; i < 4; ++i)
#pragma unroll
    for (int j = 0; j < 4; ++j) {
      long row = bm + wm + i * 16 + q * 4;
      long col = bn + wn + j * 16 + r;
#pragma unroll
      for (int rr = 0; rr < 4; ++rr) {
        if constexpr (F32OUT) ((float*)Cv)[(row + rr) * N + col] = acc[i][j][rr];
        else                  ((bf16*)Cv)[(row + rr) * N + col] = (bf16)acc[i][j][rr];
      }
    }
}

// ---------------------------------------------------------------- a/b proj -> exp(g), beta
__global__ __launch_bounds__(256)
void proj_ab(const void* __restrict__ hsr, const void* __restrict__ War,
             const void* __restrict__ Wbr, const void* __restrict__ A_logr,
             const void* __restrict__ dtbr,
             float* __restrict__ eg, float* __restrict__ bet,
             const unsigned* __restrict__ flagp) {
  const bool f32g = (*flagp != 0);
  const int s = blockIdx.x;
  const int t = threadIdx.x;
  const int o = t & 31;        // 0..15: a-head, 16..31: b-head
  const int part = t >> 5;     // 8 K-partitions of 256 elements
  const int h = o & 15;
  const int kbeg = part * 256;
  float a0 = 0.f, a1 = 0.f;
  if (f32g) {
    const f32x4* x4 = (const f32x4*)((const float*)hsr + (long)s * HIDDEN + kbeg);
    const f32x4* w4 = (const f32x4*)((const float*)((o < 16) ? War : Wbr) + (long)h * HIDDEN + kbeg);
#pragma unroll 8
    for (int k4 = 0; k4 < 64; ++k4) {
      f32x4 xv = x4[k4], wv = w4[k4];
      a0 += xv[0] * wv[0] + xv[1] * wv[1];
      a1 += xv[2] * wv[2] + xv[3] * wv[3];
    }
  } else {
    const bf16x8* x8 = (const bf16x8*)((const bf16*)hsr + (long)s * HIDDEN + kbeg);
    const bf16x8* w8 = (const bf16x8*)((const bf16*)((o < 16) ? War : Wbr) + (long)h * HIDDEN + kbeg);
#pragma unroll 8
    for (int k8 = 0; k8 < 32; ++k8) {
      bf16x8 xv = x8[k8], wv = w8[k8];
#pragma unroll
      for (int j = 0; j < 4; ++j) a0 += (float)xv[j] * (float)wv[j];
#pragma unroll
      for (int j = 4; j < 8; ++j) a1 += (float)xv[j] * (float)wv[j];
    }
  }
  __shared__ float red[256];
  red[t] = a0 + a1;
  __syncthreads();
  if (t < 32) {
    float a = 0.f;
#pragma unroll
    for (int p = 0; p < 8; ++p) a += red[t + p * 32];
    const int hh = t & 15;
    if (t < 16) {
      float alog = f32g ? ((const float*)A_logr)[hh] : b2f(((const u16*)A_logr)[hh]);
      float dtb  = f32g ? ((const float*)dtbr)[hh]   : b2f(((const u16*)dtbr)[hh]);
      float xx = a + dtb;
      float sp = fmaxf(xx, 0.f) + log1pf(__expf(-fabsf(xx)));   // stable softplus
      eg[(long)s * NH + hh] = __expf(-__expf(alog) * sp);
    } else {
      bet[(long)s * NH + hh] = sigmoidf_(a);
    }
  }
}

// ---------------------------------------------------------------- conv + SiLU + l2norm
__global__ __launch_bounds__(256)
void conv_norm(const bf16* __restrict__ mixed, const void* __restrict__ convwr,
               bf16* __restrict__ qbuf, bf16* __restrict__ kbuf, bf16* __restrict__ vbuf,
               const unsigned* __restrict__ flagp) {
  const bool f32g = (*flagp != 0);
  const int s = blockIdx.x;
  const int c = blockIdx.y * 256 + threadIdx.x;
  float w0, w1, w2, w3;
  if (f32g) {
    const float* wp = (const float*)convwr + (long)c * 4;
    w0 = wp[0]; w1 = wp[1]; w2 = wp[2]; w3 = wp[3];
  } else {
    const u16* wp = (const u16*)convwr + (long)c * 4;
    w0 = b2f(wp[0]); w1 = b2f(wp[1]); w2 = b2f(wp[2]); w3 = b2f(wp[3]);
  }
  float acc = w3 * (float)mixed[(long)s * CONV_DIM + c];
  if (s >= 1) acc += w2 * (float)mixed[(long)(s - 1) * CONV_DIM + c];
  if (s >= 2) acc += w1 * (float)mixed[(long)(s - 2) * CONV_DIM + c];
  if (s >= 3) acc += w0 * (float)mixed[(long)(s - 3) * CONV_DIM + c];
  float y = acc * sigmoidf_(acc);  // SiLU
  if (c < 2 * KEY_DIM) {           // q or k: l2norm over the 64-ch head group (one wave)
    float ss = y * y;
    ss += __shfl_xor(ss, 1);  ss += __shfl_xor(ss, 2);  ss += __shfl_xor(ss, 4);
    ss += __shfl_xor(ss, 8);  ss += __shfl_xor(ss, 16); ss += __shfl_xor(ss, 32);
    float scale = rsqrtf(ss + 1e-6f);
    if (c < KEY_DIM) scale *= 0.125f;  // q * 1/sqrt(DK)
    y *= scale;
  }
  if (c < KEY_DIM)            qbuf[(long)s * KEY_DIM + c] = (bf16)y;
  else if (c < 2 * KEY_DIM)   kbuf[(long)s * KEY_DIM + (c - KEY_DIM)] = (bf16)y;
  else                        vbuf[(long)s * VAL_DIM + (c - 2 * KEY_DIM)] = (bf16)y;
}

// ---------------------------------------------------------------- delta-rule scan
// Column (h,v) owned by 8 consecutive lanes (kk=0..7); lane holds S[kk*8..kk*8+8)[v].
__global__ __launch_bounds__(256)
void scan_kernel(const bf16* __restrict__ qbuf, const bf16* __restrict__ kbuf,
                 const bf16* __restrict__ vbuf, const float* __restrict__ eg,
                 const float* __restrict__ bet, bf16* __restrict__ core) {
  const int t   = threadIdx.x;
  const int gid = blockIdx.x * 256 + t;
  const int col = gid >> 3;       // 0..2047
  const int kk  = t & 7;
  const int h   = col >> 7;
  const int v   = col & 127;

  const bf16* kb = kbuf + h * DKv + kk * 8;
  const bf16* qb = qbuf + h * DKv + kk * 8;
  const bf16* vb = vbuf + h * DVv + v;

  float S[8];
#pragma unroll
  for (int j = 0; j < 8; ++j) S[j] = 0.f;

  bf16x8 kn = *(const bf16x8*)kb;
  bf16x8 qn = *(const bf16x8*)qb;
  float vn  = (float)*vb;
  float egn = eg[h], btn = bet[h];

  for (int s = 0; s < SEQ; ++s) {
    bf16x8 kc = kn, qc = qn;
    float vv = vn, d = egn, bt = btn;
    if (s + 1 < SEQ) {               // prefetch next step (independent of state chain)
      long offk = (long)(s + 1) * KEY_DIM;
      kn = *(const bf16x8*)(kb + offk);
      qn = *(const bf16x8*)(qb + offk);
      vn = (float)vb[(long)(s + 1) * VAL_DIM];
      egn = eg[(long)(s + 1) * NH + h]; btn = bet[(long)(s + 1) * NH + h];
    }
    float kf[8], qf[8];
#pragma unroll
    for (int j = 0; j < 8; ++j) { kf[j] = (float)kc[j]; qf[j] = (float)qc[j]; }
    float p0 = 0.f, p1 = 0.f;
#pragma unroll
    for (int j = 0; j < 4; ++j) { S[j]     *= d; p0 += kf[j]     * S[j]; }
#pragma unroll
    for (int j = 0; j < 4; ++j) { S[4 + j] *= d; p1 += kf[4 + j] * S[4 + j]; }
    float kv = p0 + p1;
    kv += __shfl_xor(kv, 1); kv += __shfl_xor(kv, 2); kv += __shfl_xor(kv, 4);
    float delta = (vv - kv) * bt;
    float o0 = 0.f, o1 = 0.f;
#pragma unroll
    for (int j = 0; j < 4; ++j) { S[j]     += kf[j]     * delta; o0 += qf[j]     * S[j]; }
#pragma unroll
    for (int j = 0; j < 4; ++j) { S[4 + j] += kf[4 + j] * delta; o1 += qf[4 + j] * S[4 + j]; }
    float o = o0 + o1;
    o += __shfl_xor(o, 1); o += __shfl_xor(o, 2); o += __shfl_xor(o, 4);
    if (kk == 0) core[(long)s * VAL_DIM + h * DVv + v] = (bf16)o;
  }
}

// ---------------------------------------------------------------- RMSNorm + SiLU(z) gate
__global__ __launch_bounds__(256)
void gate_norm(const bf16* __restrict__ core, const bf16* __restrict__ zb,
               const void* __restrict__ normwr, bf16* __restrict__ gated,
               const unsigned* __restrict__ flagp) {
  const bool f32g = (*flagp != 0);
  const int s  = blockIdx.x;
  const int t  = threadIdx.x;
  const int h  = t >> 4;
  const int li = t & 15;           // 16 lanes per head; 8 dv each
  const long base = (long)s * VAL_DIM + h * DVv + li * 8;
  bf16x8 c8 = *(const bf16x8*)(core + base);
  bf16x8 z8 = *(const bf16x8*)(zb + base);
  float x[8], z[8], nw[8];
  float ss = 0.f;
#pragma unroll
  for (int j = 0; j < 8; ++j) { x[j] = (float)c8[j]; z[j] = (float)z8[j]; ss += x[j] * x[j]; }
  if (f32g) {
    const float* np_ = (const float*)normwr + li * 8;
#pragma unroll
    for (int j = 0; j < 8; ++j) nw[j] = np_[j];
  } else {
    const u16* np_ = (const u16*)normwr + li * 8;
#pragma unroll
    for (int j = 0; j < 8; ++j) nw[j] = b2f(np_[j]);
  }
  ss += __shfl_xor(ss, 1); ss += __shfl_xor(ss, 2);
  ss += __shfl_xor(ss, 4); ss += __shfl_xor(ss, 8);
  float scale = rsqrtf(ss * (1.f / 128.f) + 1e-6f);
#pragma unroll
  for (int j = 0; j < 8; ++j) {
    float y = x[j] * scale * nw[j];
    y *= z[j] * sigmoidf_(z[j]);   // SiLU(z) gate
    gated[base + j] = (bf16)y;
  }
}

// ---------------------------------------------------------------- launcher
extern "C" void kernel_launch(void* const* d_in, const int* in_sizes, int n_in,
                              void* d_out, int out_size, void* d_ws, size_t ws_size,
                              hipStream_t stream) {
  char* ws = (char*)d_ws;
  bf16* mixed = (bf16*)ws;                       // [0,16M)
  bf16* qbuf  = (bf16*)(ws + (16u << 20));       // [16M,20M)
  bf16* kbuf  = (bf16*)(ws + (20u << 20));       // [20M,24M)
  bf16* zbuf  = (bf16*)ws;                       // [0,8M)  after conv
  bf16* corep = (bf16*)(ws + (8u << 20));        // [8M,16M) after conv
  bf16* gated = (bf16*)(ws + (16u << 20));       // [16M,24M) after scan
  float* egp  = (float*)(ws + (24u << 20));
  float* betp = (float*)(ws + (24u << 20) + (128u << 10));
  unsigned* flagp = (unsigned*)(ws + (24u << 20) + (256u << 10));
  bf16* vbuf  = (bf16*)d_out;                    // first 8M of 16M f32 d_out; overwritten

  detect_dtype<<<1, 64, 0, stream>>>((const u16*)d_in[0], flagp);
  proj_ab<<<SEQ, 256, 0, stream>>>(d_in[0], d_in[2], d_in[3], d_in[6], d_in[7], egp, betp, flagp);
  gemm_nt<false><<<dim3(CONV_DIM / 128, SEQ / 128), 256, 0, stream>>>(d_in[0], d_in[1], mixed, CONV_DIM, HIDDEN, flagp, 1, 1);
  conv_norm<<<dim3(SEQ, CONV_DIM / 256), 256, 0, stream>>>(mixed, d_in[5], qbuf, kbuf, vbuf, flagp);
  gemm_nt<false><<<dim3(VAL_DIM / 128, SEQ / 128), 256, 0, stream>>>(d_in[0], d_in[4], zbuf, VAL_DIM, HIDDEN, flagp, 1, 1);
  scan_kernel<<<(NH * DVv * 8) / 256, 256, 0, stream>>>(qbuf, kbuf, vbuf, egp, betp, corep);
  gate_norm<<<SEQ, 256, 0, stream>>>(corep, zbuf, d_in[8], gated, flagp);
  gemm_nt<true><<<dim3(HIDDEN / 128, SEQ / 128), 256, 0, stream>>>(gated, d_in[9], d_out, HIDDEN, VAL_DIM, flagp, 0, 1);
}

// Round 7
// 838.157 us; speedup vs baseline: 1.7385x; 1.7385x over previous
//
#include <hip/hip_runtime.h>
#include <stdint.h>

// LinearAttention (gated delta rule), S=2048, HID=2048, H=16, DK=64, DV=128, conv K=4.
// Established: inputs f32 (runtime-detected), output f32. r6 passed at 1457 us.
// r7: (1) scan rewritten: 16 lanes/col, DPP reduce, 8-step double-banked reg prefetch
//     (was: 8 lanes, shfl(ds_permute), 1-step prefetch -> 848 us latency-bound).
//     (2) if ws_size permits (>=48.5 MiB): pre-convert hs/W* to bf16 so all GEMMs use
//     the fast global_load_lds path; else r6 fallback (in-kernel f32 cvt staging).
//
// Pipeline: detect -> proj_ab -> [cvt] -> gemm(QKV) -> conv+SiLU+l2norm -> gemm(Z)
//           -> scan -> RMSNorm*SiLU(z) gate -> gemm(out, f32) -> d_out

#define SEQ 2048
#define HIDDEN 2048
#define NH 16
#define DKv 64
#define DVv 128
#define KEY_DIM 1024
#define VAL_DIM 2048
#define CONV_DIM 4096

typedef __bf16 bf16;
typedef unsigned short u16;
typedef __attribute__((ext_vector_type(8))) __bf16 bf16x8;
typedef __attribute__((ext_vector_type(4))) __bf16 bf16x4;
typedef __attribute__((ext_vector_type(4))) float f32x4;

__device__ __forceinline__ float b2f(u16 u) {
  union { unsigned int i; float f; } c; c.i = ((unsigned int)u) << 16; return c.f;
}
__device__ __forceinline__ float sigmoidf_(float x) { return 1.0f / (1.0f + __expf(-x)); }

// ---------------------------------------------------------------- dtype detector
__global__ void detect_dtype(const u16* __restrict__ p, unsigned* __restrict__ flag) {
  int lane = threadIdx.x;  // 64 threads
  int cnt = 0;
  for (int w = lane; w < 2048; w += 64) {
    unsigned e = (p[2 * w] >> 7) & 0xFF;
    if (e < 64) cnt++;
  }
  cnt += __shfl_xor(cnt, 1);  cnt += __shfl_xor(cnt, 2);  cnt += __shfl_xor(cnt, 4);
  cnt += __shfl_xor(cnt, 8);  cnt += __shfl_xor(cnt, 16); cnt += __shfl_xor(cnt, 32);
  if (lane == 0) *flag = (cnt > 64) ? 1u : 0u;   // 1 = inputs are f32
}

// ---------------------------------------------------------------- f32 -> bf16 convert
__global__ __launch_bounds__(256)
void cvt_bf16(const void* __restrict__ src, bf16* __restrict__ dst, long n,
              const unsigned* __restrict__ flagp) {
  long i = ((long)blockIdx.x * 256 + threadIdx.x) * 8;
  if (i >= n) return;
  if (*flagp) {
    const f32x4* s = (const f32x4*)((const float*)src + i);
    f32x4 a = s[0], b = s[1];
    bf16x8 o;
#pragma unroll
    for (int j = 0; j < 4; ++j) { o[j] = (bf16)a[j]; o[4 + j] = (bf16)b[j]; }
    *(bf16x8*)(dst + i) = o;
  } else {
    *(bf16x8*)(dst + i) = *(const bf16x8*)((const bf16*)src + i);
  }
}

// ---------------------------------------------------------------- GEMM (NT)
// C[M,N] = A[M,K] @ B[N,K]^T, f32 accum; C dtype = F32OUT ? f32 : bf16.
// useA/useB=1 -> honor flag (f32 cvt-stage via ds_write_b128); 0 -> bf16 global_load_lds.
// 128x128 tile, BK=32, 4 waves, mfma_f32_16x16x32_bf16.
template<bool F32OUT>
__global__ __launch_bounds__(256, 2)
void gemm_nt(const void* __restrict__ Araw, const void* __restrict__ Braw,
             void* __restrict__ Cv, int N, int K,
             const unsigned* __restrict__ flagp, int useA, int useB) {
  __shared__ __align__(16) bf16 As[128 * 32];
  __shared__ __align__(16) bf16 Bs[128 * 32];
  const bool f32g = (*flagp != 0);
  const bool fA = useA && f32g;
  const bool fB = useB && f32g;
  const int tid  = threadIdx.x;
  const int lane = tid & 63;
  const int wv   = tid >> 6;
  const int wm   = (wv & 1) << 6;
  const int wn   = (wv >> 1) << 6;
  const long bm  = (long)blockIdx.y * 128;
  const long bn  = (long)blockIdx.x * 128;

  f32x4 acc[4][4] = {};

  for (int k0 = 0; k0 < K; k0 += 32) {
#pragma unroll
    for (int it = 0; it < 2; ++it) {
      int e   = (it * 256 + tid) * 8;
      int row = e >> 5;
      int col = e & 31;
      long offA = (bm + row) * (long)K + (k0 + col);
      long offB = (bn + row) * (long)K + (k0 + col);
      if (fA) {
        const float* g = (const float*)Araw + offA;
        f32x4 u0 = *(const f32x4*)g, u1 = *(const f32x4*)(g + 4);
        bf16x8 bv;
#pragma unroll
        for (int j = 0; j < 4; ++j) { bv[j] = (bf16)u0[j]; bv[4 + j] = (bf16)u1[j]; }
        *(bf16x8*)&As[e] = bv;
      } else {
        const bf16* g = (const bf16*)Araw + offA;
        __builtin_amdgcn_global_load_lds(
            (__attribute__((address_space(1))) const void*)g,
            (__attribute__((address_space(3))) void*)&As[e], 16, 0, 0);
      }
      if (fB) {
        const float* g = (const float*)Braw + offB;
        f32x4 u0 = *(const f32x4*)g, u1 = *(const f32x4*)(g + 4);
        bf16x8 bv;
#pragma unroll
        for (int j = 0; j < 4; ++j) { bv[j] = (bf16)u0[j]; bv[4 + j] = (bf16)u1[j]; }
        *(bf16x8*)&Bs[e] = bv;
      } else {
        const bf16* g = (const bf16*)Braw + offB;
        __builtin_amdgcn_global_load_lds(
            (__attribute__((address_space(1))) const void*)g,
            (__attribute__((address_space(3))) void*)&Bs[e], 16, 0, 0);
      }
    }
    __syncthreads();

    const bf16x8* As8 = (const bf16x8*)As;
    const bf16x8* Bs8 = (const bf16x8*)Bs;
    const int r = lane & 15, q = lane >> 4;
    bf16x8 af[4], bfr[4];
#pragma unroll
    for (int i = 0; i < 4; ++i) af[i]  = As8[(wm + i * 16 + r) * 4 + q];
#pragma unroll
    for (int j = 0; j < 4; ++j) bfr[j] = Bs8[(wn + j * 16 + r) * 4 + q];
#pragma unroll
    for (int i = 0; i < 4; ++i)
#pragma unroll
      for (int j = 0; j < 4; ++j)
        acc[i][j] = __builtin_amdgcn_mfma_f32_16x16x32_bf16(af[i], bfr[j], acc[i][j], 0, 0, 0);
    __syncthreads();
  }

  const int r = lane & 15, q = lane >> 4;
#pragma unroll
  for (int i = 0; i < 4; ++i)
#pragma unroll
    for (int j = 0; j < 4; ++j) {
      long row = bm + wm + i * 16 + q * 4;
      long col = bn + wn + j * 16 + r;
#pragma unroll
      for (int rr = 0; rr < 4; ++rr) {
        if constexpr (F32OUT) ((float*)Cv)[(row + rr) * N + col] = acc[i][j][rr];
        else                  ((bf16*)Cv)[(row + rr) * N + col] = (bf16)acc[i][j][rr];
      }
    }
}

// ---------------------------------------------------------------- a/b proj -> exp(g), beta
__global__ __launch_bounds__(256)
void proj_ab(const void* __restrict__ hsr, const void* __restrict__ War,
             const void* __restrict__ Wbr, const void* __restrict__ A_logr,
             const void* __restrict__ dtbr,
             float* __restrict__ eg, float* __restrict__ bet,
             const unsigned* __restrict__ flagp) {
  const bool f32g = (*flagp != 0);
  const int s = blockIdx.x;
  const int t = threadIdx.x;
  const int o = t & 31;
  const int part = t >> 5;
  const int h = o & 15;
  const int kbeg = part * 256;
  float a0 = 0.f, a1 = 0.f;
  if (f32g) {
    const f32x4* x4 = (const f32x4*)((const float*)hsr + (long)s * HIDDEN + kbeg);
    const f32x4* w4 = (const f32x4*)((const float*)((o < 16) ? War : Wbr) + (long)h * HIDDEN + kbeg);
#pragma unroll 8
    for (int k4 = 0; k4 < 64; ++k4) {
      f32x4 xv = x4[k4], wv = w4[k4];
      a0 += xv[0] * wv[0] + xv[1] * wv[1];
      a1 += xv[2] * wv[2] + xv[3] * wv[3];
    }
  } else {
    const bf16x8* x8 = (const bf16x8*)((const bf16*)hsr + (long)s * HIDDEN + kbeg);
    const bf16x8* w8 = (const bf16x8*)((const bf16*)((o < 16) ? War : Wbr) + (long)h * HIDDEN + kbeg);
#pragma unroll 8
    for (int k8 = 0; k8 < 32; ++k8) {
      bf16x8 xv = x8[k8], wv = w8[k8];
#pragma unroll
      for (int j = 0; j < 4; ++j) a0 += (float)xv[j] * (float)wv[j];
#pragma unroll
      for (int j = 4; j < 8; ++j) a1 += (float)xv[j] * (float)wv[j];
    }
  }
  __shared__ float red[256];
  red[t] = a0 + a1;
  __syncthreads();
  if (t < 32) {
    float a = 0.f;
#pragma unroll
    for (int p = 0; p < 8; ++p) a += red[t + p * 32];
    const int hh = t & 15;
    if (t < 16) {
      float alog = f32g ? ((const float*)A_logr)[hh] : b2f(((const u16*)A_logr)[hh]);
      float dtb  = f32g ? ((const float*)dtbr)[hh]   : b2f(((const u16*)dtbr)[hh]);
      float xx = a + dtb;
      float sp = fmaxf(xx, 0.f) + log1pf(__expf(-fabsf(xx)));   // stable softplus
      eg[(long)s * NH + hh] = __expf(-__expf(alog) * sp);
    } else {
      bet[(long)s * NH + hh] = sigmoidf_(a);
    }
  }
}

// ---------------------------------------------------------------- conv + SiLU + l2norm
__global__ __launch_bounds__(256)
void conv_norm(const bf16* __restrict__ mixed, const void* __restrict__ convwr,
               bf16* __restrict__ qbuf, bf16* __restrict__ kbuf, bf16* __restrict__ vbuf,
               const unsigned* __restrict__ flagp) {
  const bool f32g = (*flagp != 0);
  const int s = blockIdx.x;
  const int c = blockIdx.y * 256 + threadIdx.x;
  float w0, w1, w2, w3;
  if (f32g) {
    const float* wp = (const float*)convwr + (long)c * 4;
    w0 = wp[0]; w1 = wp[1]; w2 = wp[2]; w3 = wp[3];
  } else {
    const u16* wp = (const u16*)convwr + (long)c * 4;
    w0 = b2f(wp[0]); w1 = b2f(wp[1]); w2 = b2f(wp[2]); w3 = b2f(wp[3]);
  }
  float acc = w3 * (float)mixed[(long)s * CONV_DIM + c];
  if (s >= 1) acc += w2 * (float)mixed[(long)(s - 1) * CONV_DIM + c];
  if (s >= 2) acc += w1 * (float)mixed[(long)(s - 2) * CONV_DIM + c];
  if (s >= 3) acc += w0 * (float)mixed[(long)(s - 3) * CONV_DIM + c];
  float y = acc * sigmoidf_(acc);  // SiLU
  if (c < 2 * KEY_DIM) {           // q or k: l2norm over the 64-ch head group (one wave)
    float ss = y * y;
    ss += __shfl_xor(ss, 1);  ss += __shfl_xor(ss, 2);  ss += __shfl_xor(ss, 4);
    ss += __shfl_xor(ss, 8);  ss += __shfl_xor(ss, 16); ss += __shfl_xor(ss, 32);
    float scale = rsqrtf(ss + 1e-6f);
    if (c < KEY_DIM) scale *= 0.125f;  // q * 1/sqrt(DK)
    y *= scale;
  }
  if (c < KEY_DIM)            qbuf[(long)s * KEY_DIM + c] = (bf16)y;
  else if (c < 2 * KEY_DIM)   kbuf[(long)s * KEY_DIM + (c - KEY_DIM)] = (bf16)y;
  else                        vbuf[(long)s * VAL_DIM + (c - 2 * KEY_DIM)] = (bf16)y;
}

// ---------------------------------------------------------------- delta-rule scan
// Column (h,v) owned by 16 lanes (L=0..15, one DPP row); lane holds S[L*4..L*4+4)[v].
// DPP xor-add reduce: quad_perm xor1 (0xB1), xor2 (0x4E), row_half_mirror (0x141, xor4),
// row_mirror (0x140, xor8). 8-step double-banked register prefetch hides load latency.
template<int CTRL>
__device__ __forceinline__ float dpp_add(float x) {
  int y = __builtin_amdgcn_update_dpp(0, __float_as_int(x), CTRL, 0xF, 0xF, true);
  return x + __int_as_float(y);
}

#define PF8(KA, QA, VA, EA, BA, SBASE)                                   \
  _Pragma("unroll")                                                      \
  for (int u = 0; u < 8; ++u) {                                          \
    long ss = (long)(SBASE) + u;                                         \
    KA[u] = *(const bf16x4*)(kp + ss * KEY_DIM);                         \
    QA[u] = *(const bf16x4*)(qp + ss * KEY_DIM);                         \
    VA[u] = (float)vp[ss * VAL_DIM];                                     \
    EA[u] = egp_[ss * NH];                                               \
    BA[u] = btp_[ss * NH];                                               \
  }

#define STEP8(KA, QA, VA, EA, BA, SBASE)                                 \
  _Pragma("unroll")                                                      \
  for (int u = 0; u < 8; ++u) {                                          \
    float d = EA[u];                                                     \
    float k0 = (float)KA[u][0], k1 = (float)KA[u][1],                    \
          k2 = (float)KA[u][2], k3 = (float)KA[u][3];                    \
    S0 *= d; S1 *= d; S2 *= d; S3 *= d;                                  \
    float p = (k0 * S0 + k1 * S1) + (k2 * S2 + k3 * S3);                 \
    p = dpp_add<0xB1>(p);  p = dpp_add<0x4E>(p);                         \
    p = dpp_add<0x141>(p); p = dpp_add<0x140>(p);                        \
    float delta = (VA[u] - p) * BA[u];                                   \
    S0 += k0 * delta; S1 += k1 * delta;                                  \
    S2 += k2 * delta; S3 += k3 * delta;                                  \
    float q0 = (float)QA[u][0], q1 = (float)QA[u][1],                    \
          q2 = (float)QA[u][2], q3 = (float)QA[u][3];                    \
    float o = (q0 * S0 + q1 * S1) + (q2 * S2 + q3 * S3);                 \
    o = dpp_add<0xB1>(o);  o = dpp_add<0x4E>(o);                         \
    o = dpp_add<0x141>(o); o = dpp_add<0x140>(o);                        \
    if (L == 0)                                                          \
      core[((long)(SBASE) + u) * VAL_DIM + h * DVv + v] = (bf16)o;       \
  }

__global__ __launch_bounds__(256)
void scan_kernel(const bf16* __restrict__ qbuf, const bf16* __restrict__ kbuf,
                 const bf16* __restrict__ vbuf, const float* __restrict__ eg,
                 const float* __restrict__ bet, bf16* __restrict__ core) {
  const int t   = threadIdx.x;
  const int col = blockIdx.x * 16 + (t >> 4);  // 0..2047; block covers 16 v of one head
  const int L   = t & 15;
  const int h   = col >> 7;
  const int v   = col & 127;

  const bf16*  kp   = kbuf + h * DKv + L * 4;
  const bf16*  qp   = qbuf + h * DKv + L * 4;
  const bf16*  vp   = vbuf + h * DVv + v;
  const float* egp_ = eg + h;
  const float* btp_ = bet + h;

  float S0 = 0.f, S1 = 0.f, S2 = 0.f, S3 = 0.f;

  bf16x4 kA[8], qA[8], kB[8], qB[8];
  float  vA[8], eA[8], bA[8], vB[8], eB[8], bB[8];

  PF8(kA, qA, vA, eA, bA, 0);
  for (int s0 = 0; s0 < SEQ; s0 += 16) {
    PF8(kB, qB, vB, eB, bB, s0 + 8);       // always valid: s0+15 <= 2047
    STEP8(kA, qA, vA, eA, bA, s0);
    if (s0 + 16 < SEQ) { PF8(kA, qA, vA, eA, bA, s0 + 16); }
    STEP8(kB, qB, vB, eB, bB, s0 + 8);
  }
}

// ---------------------------------------------------------------- RMSNorm + SiLU(z) gate
__global__ __launch_bounds__(256)
void gate_norm(const bf16* __restrict__ core, const bf16* __restrict__ zb,
               const void* __restrict__ normwr, bf16* __restrict__ gated,
               const unsigned* __restrict__ flagp) {
  const bool f32g = (*flagp != 0);
  const int s  = blockIdx.x;
  const int t  = threadIdx.x;
  const int h  = t >> 4;
  const int li = t & 15;
  const long base = (long)s * VAL_DIM + h * DVv + li * 8;
  bf16x8 c8 = *(const bf16x8*)(core + base);
  bf16x8 z8 = *(const bf16x8*)(zb + base);
  float x[8], z[8], nw[8];
  float ss = 0.f;
#pragma unroll
  for (int j = 0; j < 8; ++j) { x[j] = (float)c8[j]; z[j] = (float)z8[j]; ss += x[j] * x[j]; }
  if (f32g) {
    const float* np_ = (const float*)normwr + li * 8;
#pragma unroll
    for (int j = 0; j < 8; ++j) nw[j] = np_[j];
  } else {
    const u16* np_ = (const u16*)normwr + li * 8;
#pragma unroll
    for (int j = 0; j < 8; ++j) nw[j] = b2f(np_[j]);
  }
  ss += __shfl_xor(ss, 1); ss += __shfl_xor(ss, 2);
  ss += __shfl_xor(ss, 4); ss += __shfl_xor(ss, 8);
  float scale = rsqrtf(ss * (1.f / 128.f) + 1e-6f);
#pragma unroll
  for (int j = 0; j < 8; ++j) {
    float y = x[j] * scale * nw[j];
    y *= z[j] * sigmoidf_(z[j]);
    gated[base + j] = (bf16)y;
  }
}

// ---------------------------------------------------------------- launcher
extern "C" void kernel_launch(void* const* d_in, const int* in_sizes, int n_in,
                              void* d_out, int out_size, void* d_ws, size_t ws_size,
                              hipStream_t stream) {
  char* ws = (char*)d_ws;
  const bool big = ws_size >= ((48u << 20) + (512u << 10));

  if (big) {
    // Big layout (peak 48.26 MiB):
    //   [0,8M)   hsb bf16            [8,24M)  wqkvb bf16 (-> after gemm1: wzb @8M, zbuf @16M)
    //   [24,40M) mixed bf16          (-> after conv: core @24M, gated @32M)
    //   [40,44M) qbuf  [44,48M) kbuf (-> after scan: woutb @40M)
    //   [48M..)  eg | beta | flag.   vbuf = d_out first 8 MiB (overwritten by gemm3).
    bf16* hsb   = (bf16*)ws;
    bf16* wqkvb = (bf16*)(ws + (8u << 20));
    bf16* wzb   = (bf16*)(ws + (8u << 20));
    bf16* zbuf  = (bf16*)(ws + (16u << 20));
    bf16* mixed = (bf16*)(ws + (24u << 20));
    bf16* corep = (bf16*)(ws + (24u << 20));
    bf16* gated = (bf16*)(ws + (32u << 20));
    bf16* qbuf  = (bf16*)(ws + (40u << 20));
    bf16* kbuf  = (bf16*)(ws + (44u << 20));
    bf16* woutb = (bf16*)(ws + (40u << 20));
    float* egp  = (float*)(ws + (48u << 20));
    float* betp = (float*)(ws + (48u << 20) + (128u << 10));
    unsigned* flagp = (unsigned*)(ws + (48u << 20) + (256u << 10));
    bf16* vbuf  = (bf16*)d_out;

    detect_dtype<<<1, 64, 0, stream>>>((const u16*)d_in[0], flagp);
    proj_ab<<<SEQ, 256, 0, stream>>>(d_in[0], d_in[2], d_in[3], d_in[6], d_in[7], egp, betp, flagp);
    cvt_bf16<<<(SEQ * HIDDEN) / 2048, 256, 0, stream>>>(d_in[0], hsb, (long)SEQ * HIDDEN, flagp);
    cvt_bf16<<<(CONV_DIM * HIDDEN) / 2048, 256, 0, stream>>>(d_in[1], wqkvb, (long)CONV_DIM * HIDDEN, flagp);
    gemm_nt<false><<<dim3(CONV_DIM / 128, SEQ / 128), 256, 0, stream>>>(hsb, wqkvb, mixed, CONV_DIM, HIDDEN, flagp, 0, 0);
    cvt_bf16<<<(VAL_DIM * HIDDEN) / 2048, 256, 0, stream>>>(d_in[4], wzb, (long)VAL_DIM * HIDDEN, flagp);
    conv_norm<<<dim3(SEQ, CONV_DIM / 256), 256, 0, stream>>>(mixed, d_in[5], qbuf, kbuf, vbuf, flagp);
    gemm_nt<false><<<dim3(VAL_DIM / 128, SEQ / 128), 256, 0, stream>>>(hsb, wzb, zbuf, VAL_DIM, HIDDEN, flagp, 0, 0);
    scan_kernel<<<(NH * DVv) / 16, 256, 0, stream>>>(qbuf, kbuf, vbuf, egp, betp, corep);
    cvt_bf16<<<(HIDDEN * VAL_DIM) / 2048, 256, 0, stream>>>(d_in[9], woutb, (long)HIDDEN * VAL_DIM, flagp);
    gate_norm<<<SEQ, 256, 0, stream>>>(corep, zbuf, d_in[8], gated, flagp);
    gemm_nt<true><<<dim3(HIDDEN / 128, SEQ / 128), 256, 0, stream>>>(gated, woutb, d_out, HIDDEN, VAL_DIM, flagp, 0, 0);
  } else {
    // r6 fallback layout (peak 24.26 MiB)
    bf16* mixed = (bf16*)ws;
    bf16* qbuf  = (bf16*)(ws + (16u << 20));
    bf16* kbuf  = (bf16*)(ws + (20u << 20));
    bf16* zbuf  = (bf16*)ws;
    bf16* corep = (bf16*)(ws + (8u << 20));
    bf16* gated = (bf16*)(ws + (16u << 20));
    float* egp  = (float*)(ws + (24u << 20));
    float* betp = (float*)(ws + (24u << 20) + (128u << 10));
    unsigned* flagp = (unsigned*)(ws + (24u << 20) + (256u << 10));
    bf16* vbuf  = (bf16*)d_out;

    detect_dtype<<<1, 64, 0, stream>>>((const u16*)d_in[0], flagp);
    proj_ab<<<SEQ, 256, 0, stream>>>(d_in[0], d_in[2], d_in[3], d_in[6], d_in[7], egp, betp, flagp);
    gemm_nt<false><<<dim3(CONV_DIM / 128, SEQ / 128), 256, 0, stream>>>(d_in[0], d_in[1], mixed, CONV_DIM, HIDDEN, flagp, 1, 1);
    conv_norm<<<dim3(SEQ, CONV_DIM / 256), 256, 0, stream>>>(mixed, d_in[5], qbuf, kbuf, vbuf, flagp);
    gemm_nt<false><<<dim3(VAL_DIM / 128, SEQ / 128), 256, 0, stream>>>(d_in[0], d_in[4], zbuf, VAL_DIM, HIDDEN, flagp, 1, 1);
    scan_kernel<<<(NH * DVv) / 16, 256, 0, stream>>>(qbuf, kbuf, vbuf, egp, betp, corep);
    gate_norm<<<SEQ, 256, 0, stream>>>(corep, zbuf, d_in[8], gated, flagp);
    gemm_nt<true><<<dim3(HIDDEN / 128, SEQ / 128), 256, 0, stream>>>(gated, d_in[9], d_out, HIDDEN, VAL_DIM, flagp, 0, 1);
  }
}

// Round 8
// 749.374 us; speedup vs baseline: 1.9445x; 1.1185x over previous
//
#include <hip/hip_runtime.h>
#include <stdint.h>

// LinearAttention (gated delta rule), S=2048, HID=2048, H=16, DK=64, DV=128, conv K=4.
// Established: inputs f32 (runtime-detected), output f32. r7 passed at 838 us
// (scan 435 us latency-bound, VALUBusy 17%).
// r8: scan v3 — branch-free double-banked prefetch (deterministic vmcnt, no full
// drains) + shortened dependency chain (off-chain decay, 1-fma delta).
//
// Pipeline: detect -> proj_ab -> [cvt] -> gemm(QKV) -> conv+SiLU+l2norm -> gemm(Z)
//           -> scan -> RMSNorm*SiLU(z) gate -> gemm(out, f32) -> d_out

#define SEQ 2048
#define HIDDEN 2048
#define NH 16
#define DKv 64
#define DVv 128
#define KEY_DIM 1024
#define VAL_DIM 2048
#define CONV_DIM 4096

typedef __bf16 bf16;
typedef unsigned short u16;
typedef __attribute__((ext_vector_type(8))) __bf16 bf16x8;
typedef __attribute__((ext_vector_type(4))) __bf16 bf16x4;
typedef __attribute__((ext_vector_type(4))) float f32x4;

__device__ __forceinline__ float b2f(u16 u) {
  union { unsigned int i; float f; } c; c.i = ((unsigned int)u) << 16; return c.f;
}
__device__ __forceinline__ float sigmoidf_(float x) { return 1.0f / (1.0f + __expf(-x)); }

// ---------------------------------------------------------------- dtype detector
__global__ void detect_dtype(const u16* __restrict__ p, unsigned* __restrict__ flag) {
  int lane = threadIdx.x;  // 64 threads
  int cnt = 0;
  for (int w = lane; w < 2048; w += 64) {
    unsigned e = (p[2 * w] >> 7) & 0xFF;
    if (e < 64) cnt++;
  }
  cnt += __shfl_xor(cnt, 1);  cnt += __shfl_xor(cnt, 2);  cnt += __shfl_xor(cnt, 4);
  cnt += __shfl_xor(cnt, 8);  cnt += __shfl_xor(cnt, 16); cnt += __shfl_xor(cnt, 32);
  if (lane == 0) *flag = (cnt > 64) ? 1u : 0u;   // 1 = inputs are f32
}

// ---------------------------------------------------------------- f32 -> bf16 convert
__global__ __launch_bounds__(256)
void cvt_bf16(const void* __restrict__ src, bf16* __restrict__ dst, long n,
              const unsigned* __restrict__ flagp) {
  long i = ((long)blockIdx.x * 256 + threadIdx.x) * 8;
  if (i >= n) return;
  if (*flagp) {
    const f32x4* s = (const f32x4*)((const float*)src + i);
    f32x4 a = s[0], b = s[1];
    bf16x8 o;
#pragma unroll
    for (int j = 0; j < 4; ++j) { o[j] = (bf16)a[j]; o[4 + j] = (bf16)b[j]; }
    *(bf16x8*)(dst + i) = o;
  } else {
    *(bf16x8*)(dst + i) = *(const bf16x8*)((const bf16*)src + i);
  }
}

// ---------------------------------------------------------------- GEMM (NT)
// C[M,N] = A[M,K] @ B[N,K]^T, f32 accum; C dtype = F32OUT ? f32 : bf16.
// useA/useB=1 -> honor flag (f32 cvt-stage via ds_write_b128); 0 -> bf16 global_load_lds.
// 128x128 tile, BK=32, 4 waves, mfma_f32_16x16x32_bf16.
template<bool F32OUT>
__global__ __launch_bounds__(256, 2)
void gemm_nt(const void* __restrict__ Araw, const void* __restrict__ Braw,
             void* __restrict__ Cv, int N, int K,
             const unsigned* __restrict__ flagp, int useA, int useB) {
  __shared__ __align__(16) bf16 As[128 * 32];
  __shared__ __align__(16) bf16 Bs[128 * 32];
  const bool f32g = (*flagp != 0);
  const bool fA = useA && f32g;
  const bool fB = useB && f32g;
  const int tid  = threadIdx.x;
  const int lane = tid & 63;
  const int wv   = tid >> 6;
  const int wm   = (wv & 1) << 6;
  const int wn   = (wv >> 1) << 6;
  const long bm  = (long)blockIdx.y * 128;
  const long bn  = (long)blockIdx.x * 128;

  f32x4 acc[4][4] = {};

  for (int k0 = 0; k0 < K; k0 += 32) {
#pragma unroll
    for (int it = 0; it < 2; ++it) {
      int e   = (it * 256 + tid) * 8;
      int row = e >> 5;
      int col = e & 31;
      long offA = (bm + row) * (long)K + (k0 + col);
      long offB = (bn + row) * (long)K + (k0 + col);
      if (fA) {
        const float* g = (const float*)Araw + offA;
        f32x4 u0 = *(const f32x4*)g, u1 = *(const f32x4*)(g + 4);
        bf16x8 bv;
#pragma unroll
        for (int j = 0; j < 4; ++j) { bv[j] = (bf16)u0[j]; bv[4 + j] = (bf16)u1[j]; }
        *(bf16x8*)&As[e] = bv;
      } else {
        const bf16* g = (const bf16*)Araw + offA;
        __builtin_amdgcn_global_load_lds(
            (__attribute__((address_space(1))) const void*)g,
            (__attribute__((address_space(3))) void*)&As[e], 16, 0, 0);
      }
      if (fB) {
        const float* g = (const float*)Braw + offB;
        f32x4 u0 = *(const f32x4*)g, u1 = *(const f32x4*)(g + 4);
        bf16x8 bv;
#pragma unroll
        for (int j = 0; j < 4; ++j) { bv[j] = (bf16)u0[j]; bv[4 + j] = (bf16)u1[j]; }
        *(bf16x8*)&Bs[e] = bv;
      } else {
        const bf16* g = (const bf16*)Braw + offB;
        __builtin_amdgcn_global_load_lds(
            (__attribute__((address_space(1))) const void*)g,
            (__attribute__((address_space(3))) void*)&Bs[e], 16, 0, 0);
      }
    }
    __syncthreads();

    const bf16x8* As8 = (const bf16x8*)As;
    const bf16x8* Bs8 = (const bf16x8*)Bs;
    const int r = lane & 15, q = lane >> 4;
    bf16x8 af[4], bfr[4];
#pragma unroll
    for (int i = 0; i < 4; ++i) af[i]  = As8[(wm + i * 16 + r) * 4 + q];
#pragma unroll
    for (int j = 0; j < 4; ++j) bfr[j] = Bs8[(wn + j * 16 + r) * 4 + q];
#pragma unroll
    for (int i = 0; i < 4; ++i)
#pragma unroll
      for (int j = 0; j < 4; ++j)
        acc[i][j] = __builtin_amdgcn_mfma_f32_16x16x32_bf16(af[i], bfr[j], acc[i][j], 0, 0, 0);
    __syncthreads();
  }

  const int r = lane & 15, q = lane >> 4;
#pragma unroll
  for (int i = 0; i < 4; ++i)
#pragma unroll
    for (int j = 0; j < 4; ++j) {
      long row = bm + wm + i * 16 + q * 4;
      long col = bn + wn + j * 16 + r;
#pragma unroll
      for (int rr = 0; rr < 4; ++rr) {
        if constexpr (F32OUT) ((float*)Cv)[(row + rr) * N + col] = acc[i][j][rr];
        else                  ((bf16*)Cv)[(row + rr) * N + col] = (bf16)acc[i][j][rr];
      }
    }
}

// ---------------------------------------------------------------- a/b proj -> exp(g), beta
__global__ __launch_bounds__(256)
void proj_ab(const void* __restrict__ hsr, const void* __restrict__ War,
             const void* __restrict__ Wbr, const void* __restrict__ A_logr,
             const void* __restrict__ dtbr,
             float* __restrict__ eg, float* __restrict__ bet,
             const unsigned* __restrict__ flagp) {
  const bool f32g = (*flagp != 0);
  const int s = blockIdx.x;
  const int t = threadIdx.x;
  const int o = t & 31;
  const int part = t >> 5;
  const int h = o & 15;
  const int kbeg = part * 256;
  float a0 = 0.f, a1 = 0.f;
  if (f32g) {
    const f32x4* x4 = (const f32x4*)((const float*)hsr + (long)s * HIDDEN + kbeg);
    const f32x4* w4 = (const f32x4*)((const float*)((o < 16) ? War : Wbr) + (long)h * HIDDEN + kbeg);
#pragma unroll 8
    for (int k4 = 0; k4 < 64; ++k4) {
      f32x4 xv = x4[k4], wv = w4[k4];
      a0 += xv[0] * wv[0] + xv[1] * wv[1];
      a1 += xv[2] * wv[2] + xv[3] * wv[3];
    }
  } else {
    const bf16x8* x8 = (const bf16x8*)((const bf16*)hsr + (long)s * HIDDEN + kbeg);
    const bf16x8* w8 = (const bf16x8*)((const bf16*)((o < 16) ? War : Wbr) + (long)h * HIDDEN + kbeg);
#pragma unroll 8
    for (int k8 = 0; k8 < 32; ++k8) {
      bf16x8 xv = x8[k8], wv = w8[k8];
#pragma unroll
      for (int j = 0; j < 4; ++j) a0 += (float)xv[j] * (float)wv[j];
#pragma unroll
      for (int j = 4; j < 8; ++j) a1 += (float)xv[j] * (float)wv[j];
    }
  }
  __shared__ float red[256];
  red[t] = a0 + a1;
  __syncthreads();
  if (t < 32) {
    float a = 0.f;
#pragma unroll
    for (int p = 0; p < 8; ++p) a += red[t + p * 32];
    const int hh = t & 15;
    if (t < 16) {
      float alog = f32g ? ((const float*)A_logr)[hh] : b2f(((const u16*)A_logr)[hh]);
      float dtb  = f32g ? ((const float*)dtbr)[hh]   : b2f(((const u16*)dtbr)[hh]);
      float xx = a + dtb;
      float sp = fmaxf(xx, 0.f) + log1pf(__expf(-fabsf(xx)));   // stable softplus
      eg[(long)s * NH + hh] = __expf(-__expf(alog) * sp);
    } else {
      bet[(long)s * NH + hh] = sigmoidf_(a);
    }
  }
}

// ---------------------------------------------------------------- conv + SiLU + l2norm
__global__ __launch_bounds__(256)
void conv_norm(const bf16* __restrict__ mixed, const void* __restrict__ convwr,
               bf16* __restrict__ qbuf, bf16* __restrict__ kbuf, bf16* __restrict__ vbuf,
               const unsigned* __restrict__ flagp) {
  const bool f32g = (*flagp != 0);
  const int s = blockIdx.x;
  const int c = blockIdx.y * 256 + threadIdx.x;
  float w0, w1, w2, w3;
  if (f32g) {
    const float* wp = (const float*)convwr + (long)c * 4;
    w0 = wp[0]; w1 = wp[1]; w2 = wp[2]; w3 = wp[3];
  } else {
    const u16* wp = (const u16*)convwr + (long)c * 4;
    w0 = b2f(wp[0]); w1 = b2f(wp[1]); w2 = b2f(wp[2]); w3 = b2f(wp[3]);
  }
  float acc = w3 * (float)mixed[(long)s * CONV_DIM + c];
  if (s >= 1) acc += w2 * (float)mixed[(long)(s - 1) * CONV_DIM + c];
  if (s >= 2) acc += w1 * (float)mixed[(long)(s - 2) * CONV_DIM + c];
  if (s >= 3) acc += w0 * (float)mixed[(long)(s - 3) * CONV_DIM + c];
  float y = acc * sigmoidf_(acc);  // SiLU
  if (c < 2 * KEY_DIM) {           // q or k: l2norm over the 64-ch head group (one wave)
    float ss = y * y;
    ss += __shfl_xor(ss, 1);  ss += __shfl_xor(ss, 2);  ss += __shfl_xor(ss, 4);
    ss += __shfl_xor(ss, 8);  ss += __shfl_xor(ss, 16); ss += __shfl_xor(ss, 32);
    float scale = rsqrtf(ss + 1e-6f);
    if (c < KEY_DIM) scale *= 0.125f;  // q * 1/sqrt(DK)
    y *= scale;
  }
  if (c < KEY_DIM)            qbuf[(long)s * KEY_DIM + c] = (bf16)y;
  else if (c < 2 * KEY_DIM)   kbuf[(long)s * KEY_DIM + (c - KEY_DIM)] = (bf16)y;
  else                        vbuf[(long)s * VAL_DIM + (c - 2 * KEY_DIM)] = (bf16)y;
}

// ---------------------------------------------------------------- delta-rule scan (v3)
// Column (h,v) owned by 16 lanes (one DPP row); lane L holds S[L*4..L*4+4)[v].
// Chain per step: reduce(k.S_old) -> delta (1 fma) -> S = fma(k,delta,S*eg).
// S*eg, v*beta, eg*beta, q-side output all off-chain. Branch-free double-banked
// 8-step prefetch (deterministic vmcnt; no full drains).
template<int CTRL>
__device__ __forceinline__ float dpp_add(float x) {
  int y = __builtin_amdgcn_update_dpp(0, __float_as_int(x), CTRL, 0xF, 0xF, true);
  return x + __int_as_float(y);
}
__device__ __forceinline__ float dpp_sum16(float x) {
  x = dpp_add<0xB1>(x);   // quad_perm xor1
  x = dpp_add<0x4E>(x);   // quad_perm xor2
  x = dpp_add<0x141>(x);  // row_half_mirror (xor4)
  x = dpp_add<0x140>(x);  // row_mirror (xor8)
  return x;
}

#define PF8(K, Q, V, E, B, SBASE)                                \
  _Pragma("unroll")                                              \
  for (int u = 0; u < 8; ++u) {                                  \
    long ss = (long)(SBASE) + u;                                 \
    K[u] = *(const bf16x4*)(kp + ss * KEY_DIM);                  \
    Q[u] = *(const bf16x4*)(qp + ss * KEY_DIM);                  \
    V[u] = (float)vp[ss * VAL_DIM];                              \
    E[u] = ep[ss * NH];                                          \
    B[u] = bp[ss * NH];                                          \
  }

#define STEP8(K, Q, V, E, B, SBASE)                              \
  _Pragma("unroll")                                              \
  for (int u = 0; u < 8; ++u) {                                  \
    const float egv = E[u], btv = B[u];                          \
    const float ebt = egv * btv, vbt = V[u] * btv;               \
    const float k0 = (float)K[u][0], k1 = (float)K[u][1],        \
                k2 = (float)K[u][2], k3 = (float)K[u][3];        \
    const float D0 = S0 * egv, D1 = S1 * egv,                    \
                D2 = S2 * egv, D3 = S3 * egv;                    \
    float p = (k0 * S0 + k1 * S1) + (k2 * S2 + k3 * S3);         \
    p = dpp_sum16(p);                                            \
    const float delta = vbt - ebt * p;                           \
    S0 = fmaf(k0, delta, D0); S1 = fmaf(k1, delta, D1);          \
    S2 = fmaf(k2, delta, D2); S3 = fmaf(k3, delta, D3);          \
    const float q0 = (float)Q[u][0], q1 = (float)Q[u][1],        \
                q2 = (float)Q[u][2], q3 = (float)Q[u][3];        \
    float o = (q0 * S0 + q1 * S1) + (q2 * S2 + q3 * S3);         \
    o = dpp_sum16(o);                                            \
    if (L == 0)                                                  \
      core[((long)(SBASE) + u) * VAL_DIM + h * DVv + v] = (bf16)o; \
  }

__global__ __launch_bounds__(256)
void scan_kernel(const bf16* __restrict__ qbuf, const bf16* __restrict__ kbuf,
                 const bf16* __restrict__ vbuf, const float* __restrict__ eg,
                 const float* __restrict__ bet, bf16* __restrict__ core) {
  const int t   = threadIdx.x;
  const int col = blockIdx.x * 16 + (t >> 4);  // 16 v-columns of one head per block
  const int L   = t & 15;
  const int h   = col >> 7;
  const int v   = col & 127;

  const bf16*  kp = kbuf + h * DKv + L * 4;
  const bf16*  qp = qbuf + h * DKv + L * 4;
  const bf16*  vp = vbuf + h * DVv + v;
  const float* ep = eg + h;
  const float* bp = bet + h;

  float S0 = 0.f, S1 = 0.f, S2 = 0.f, S3 = 0.f;

  bf16x4 kA[8], qA[8], kB[8], qB[8];
  float  vA[8], eA[8], bA[8], vB[8], eB[8], bB[8];

  PF8(kA, qA, vA, eA, bA, 0);
  PF8(kB, qB, vB, eB, bB, 8);
  int s0 = 0;
  // main loop: all prefetches unconditional & in-bounds (max index 2047)
  for (; s0 < SEQ - 16; s0 += 16) {
    STEP8(kA, qA, vA, eA, bA, s0);
    PF8(kA, qA, vA, eA, bA, s0 + 16);
    STEP8(kB, qB, vB, eB, bB, s0 + 8);
    PF8(kB, qB, vB, eB, bB, s0 + 24);
  }
  // epilogue: s0 == SEQ-16; banks already loaded
  STEP8(kA, qA, vA, eA, bA, s0);
  STEP8(kB, qB, vB, eB, bB, s0 + 8);
}

// ---------------------------------------------------------------- RMSNorm + SiLU(z) gate
__global__ __launch_bounds__(256)
void gate_norm(const bf16* __restrict__ core, const bf16* __restrict__ zb,
               const void* __restrict__ normwr, bf16* __restrict__ gated,
               const unsigned* __restrict__ flagp) {
  const bool f32g = (*flagp != 0);
  const int s  = blockIdx.x;
  const int t  = threadIdx.x;
  const int h  = t >> 4;
  const int li = t & 15;
  const long base = (long)s * VAL_DIM + h * DVv + li * 8;
  bf16x8 c8 = *(const bf16x8*)(core + base);
  bf16x8 z8 = *(const bf16x8*)(zb + base);
  float x[8], z[8], nw[8];
  float ss = 0.f;
#pragma unroll
  for (int j = 0; j < 8; ++j) { x[j] = (float)c8[j]; z[j] = (float)z8[j]; ss += x[j] * x[j]; }
  if (f32g) {
    const float* np_ = (const float*)normwr + li * 8;
#pragma unroll
    for (int j = 0; j < 8; ++j) nw[j] = np_[j];
  } else {
    const u16* np_ = (const u16*)normwr + li * 8;
#pragma unroll
    for (int j = 0; j < 8; ++j) nw[j] = b2f(np_[j]);
  }
  ss += __shfl_xor(ss, 1); ss += __shfl_xor(ss, 2);
  ss += __shfl_xor(ss, 4); ss += __shfl_xor(ss, 8);
  float scale = rsqrtf(ss * (1.f / 128.f) + 1e-6f);
#pragma unroll
  for (int j = 0; j < 8; ++j) {
    float y = x[j] * scale * nw[j];
    y *= z[j] * sigmoidf_(z[j]);
    gated[base + j] = (bf16)y;
  }
}

// ---------------------------------------------------------------- launcher
extern "C" void kernel_launch(void* const* d_in, const int* in_sizes, int n_in,
                              void* d_out, int out_size, void* d_ws, size_t ws_size,
                              hipStream_t stream) {
  char* ws = (char*)d_ws;
  const bool big = ws_size >= ((48u << 20) + (512u << 10));

  if (big) {
    // Big layout (peak 48.26 MiB):
    //   [0,8M)   hsb bf16            [8,24M)  wqkvb bf16 (-> after gemm1: wzb @8M, zbuf @16M)
    //   [24,40M) mixed bf16          (-> after conv: core @24M, gated @32M)
    //   [40,44M) qbuf  [44,48M) kbuf (-> after scan: woutb @40M)
    //   [48M..)  eg | beta | flag.   vbuf = d_out first 8 MiB (overwritten by gemm3).
    bf16* hsb   = (bf16*)ws;
    bf16* wqkvb = (bf16*)(ws + (8u << 20));
    bf16* wzb   = (bf16*)(ws + (8u << 20));
    bf16* zbuf  = (bf16*)(ws + (16u << 20));
    bf16* mixed = (bf16*)(ws + (24u << 20));
    bf16* corep = (bf16*)(ws + (24u << 20));
    bf16* gated = (bf16*)(ws + (32u << 20));
    bf16* qbuf  = (bf16*)(ws + (40u << 20));
    bf16* kbuf  = (bf16*)(ws + (44u << 20));
    bf16* woutb = (bf16*)(ws + (40u << 20));
    float* egp  = (float*)(ws + (48u << 20));
    float* betp = (float*)(ws + (48u << 20) + (128u << 10));
    unsigned* flagp = (unsigned*)(ws + (48u << 20) + (256u << 10));
    bf16* vbuf  = (bf16*)d_out;

    detect_dtype<<<1, 64, 0, stream>>>((const u16*)d_in[0], flagp);
    proj_ab<<<SEQ, 256, 0, stream>>>(d_in[0], d_in[2], d_in[3], d_in[6], d_in[7], egp, betp, flagp);
    cvt_bf16<<<(SEQ * HIDDEN) / 2048, 256, 0, stream>>>(d_in[0], hsb, (long)SEQ * HIDDEN, flagp);
    cvt_bf16<<<(CONV_DIM * HIDDEN) / 2048, 256, 0, stream>>>(d_in[1], wqkvb, (long)CONV_DIM * HIDDEN, flagp);
    gemm_nt<false><<<dim3(CONV_DIM / 128, SEQ / 128), 256, 0, stream>>>(hsb, wqkvb, mixed, CONV_DIM, HIDDEN, flagp, 0, 0);
    cvt_bf16<<<(VAL_DIM * HIDDEN) / 2048, 256, 0, stream>>>(d_in[4], wzb, (long)VAL_DIM * HIDDEN, flagp);
    conv_norm<<<dim3(SEQ, CONV_DIM / 256), 256, 0, stream>>>(mixed, d_in[5], qbuf, kbuf, vbuf, flagp);
    gemm_nt<false><<<dim3(VAL_DIM / 128, SEQ / 128), 256, 0, stream>>>(hsb, wzb, zbuf, VAL_DIM, HIDDEN, flagp, 0, 0);
    scan_kernel<<<(NH * DVv) / 16, 256, 0, stream>>>(qbuf, kbuf, vbuf, egp, betp, corep);
    cvt_bf16<<<(HIDDEN * VAL_DIM) / 2048, 256, 0, stream>>>(d_in[9], woutb, (long)HIDDEN * VAL_DIM, flagp);
    gate_norm<<<SEQ, 256, 0, stream>>>(corep, zbuf, d_in[8], gated, flagp);
    gemm_nt<true><<<dim3(HIDDEN / 128, SEQ / 128), 256, 0, stream>>>(gated, woutb, d_out, HIDDEN, VAL_DIM, flagp, 0, 0);
  } else {
    // r6 fallback layout (peak 24.26 MiB)
    bf16* mixed = (bf16*)ws;
    bf16* qbuf  = (bf16*)(ws + (16u << 20));
    bf16* kbuf  = (bf16*)(ws + (20u << 20));
    bf16* zbuf  = (bf16*)ws;
    bf16* corep = (bf16*)(ws + (8u << 20));
    bf16* gated = (bf16*)(ws + (16u << 20));
    float* egp  = (float*)(ws + (24u << 20));
    float* betp = (float*)(ws + (24u << 20) + (128u << 10));
    unsigned* flagp = (unsigned*)(ws + (24u << 20) + (256u << 10));
    bf16* vbuf  = (bf16*)d_out;

    detect_dtype<<<1, 64, 0, stream>>>((const u16*)d_in[0], flagp);
    proj_ab<<<SEQ, 256, 0, stream>>>(d_in[0], d_in[2], d_in[3], d_in[6], d_in[7], egp, betp, flagp);
    gemm_nt<false><<<dim3(CONV_DIM / 128, SEQ / 128), 256, 0, stream>>>(d_in[0], d_in[1], mixed, CONV_DIM, HIDDEN, flagp, 1, 1);
    conv_norm<<<dim3(SEQ, CONV_DIM / 256), 256, 0, stream>>>(mixed, d_in[5], qbuf, kbuf, vbuf, flagp);
    gemm_nt<false><<<dim3(VAL_DIM / 128, SEQ / 128), 256, 0, stream>>>(d_in[0], d_in[4], zbuf, VAL_DIM, HIDDEN, flagp, 1, 1);
    scan_kernel<<<(NH * DVv) / 16, 256, 0, stream>>>(qbuf, kbuf, vbuf, egp, betp, corep);
    gate_norm<<<SEQ, 256, 0, stream>>>(corep, zbuf, d_in[8], gated, flagp);
    gemm_nt<true><<<dim3(HIDDEN / 128, SEQ / 128), 256, 0, stream>>>(gated, d_in[9], d_out, HIDDEN, VAL_DIM, flagp, 0, 1);
  }
}

// Round 9
// 749.059 us; speedup vs baseline: 1.9453x; 1.0004x over previous
//
#include <hip/hip_runtime.h>
#include <stdint.h>

// LinearAttention (gated delta rule), S=2048, HID=2048, H=16, DK=64, DV=128, conv K=4.
// Established: inputs f32 (runtime-detected), output f32. r8: 749 us, scan 345 us.
// r9: scan v4 — k/q/v staged in LDS via global_load_lds DMA (double-buffered 16-step
// tiles; r8's register banks didn't fit: VGPR=76 < ~112 needed, prefetch collapsed).
// z-GEMM + wout-cvt fused into the scan dispatch as extra block roles (scan uses only
// 128 blocks; rest of GPU was idle).
//
// Pipeline: detect -> proj_ab -> cvt(hs,wqkv) -> gemm(QKV) -> cvt(wz) -> conv
//           -> FUSED[scan | z-gemm | wout-cvt] -> gate -> gemm(out, f32) -> d_out

#define SEQ 2048
#define HIDDEN 2048
#define NH 16
#define DKv 64
#define DVv 128
#define KEY_DIM 1024
#define VAL_DIM 2048
#define CONV_DIM 4096

typedef __bf16 bf16;
typedef unsigned short u16;
typedef __attribute__((ext_vector_type(8))) __bf16 bf16x8;
typedef __attribute__((ext_vector_type(4))) __bf16 bf16x4;
typedef __attribute__((ext_vector_type(4))) float f32x4;

__device__ __forceinline__ float b2f(u16 u) {
  union { unsigned int i; float f; } c; c.i = ((unsigned int)u) << 16; return c.f;
}
__device__ __forceinline__ float sigmoidf_(float x) { return 1.0f / (1.0f + __expf(-x)); }

// ---------------------------------------------------------------- dtype detector
__global__ void detect_dtype(const u16* __restrict__ p, unsigned* __restrict__ flag) {
  int lane = threadIdx.x;  // 64 threads
  int cnt = 0;
  for (int w = lane; w < 2048; w += 64) {
    unsigned e = (p[2 * w] >> 7) & 0xFF;
    if (e < 64) cnt++;
  }
  cnt += __shfl_xor(cnt, 1);  cnt += __shfl_xor(cnt, 2);  cnt += __shfl_xor(cnt, 4);
  cnt += __shfl_xor(cnt, 8);  cnt += __shfl_xor(cnt, 16); cnt += __shfl_xor(cnt, 32);
  if (lane == 0) *flag = (cnt > 64) ? 1u : 0u;   // 1 = inputs are f32
}

// ---------------------------------------------------------------- f32 -> bf16 convert
__global__ __launch_bounds__(256)
void cvt_bf16(const void* __restrict__ src, bf16* __restrict__ dst, long n,
              const unsigned* __restrict__ flagp) {
  long i = ((long)blockIdx.x * 256 + threadIdx.x) * 8;
  if (i >= n) return;
  if (*flagp) {
    const f32x4* s = (const f32x4*)((const float*)src + i);
    f32x4 a = s[0], b = s[1];
    bf16x8 o;
#pragma unroll
    for (int j = 0; j < 4; ++j) { o[j] = (bf16)a[j]; o[4 + j] = (bf16)b[j]; }
    *(bf16x8*)(dst + i) = o;
  } else {
    *(bf16x8*)(dst + i) = *(const bf16x8*)((const bf16*)src + i);
  }
}

// ---------------------------------------------------------------- GEMM (NT) standalone
template<bool F32OUT>
__global__ __launch_bounds__(256, 2)
void gemm_nt(const void* __restrict__ Araw, const void* __restrict__ Braw,
             void* __restrict__ Cv, int N, int K,
             const unsigned* __restrict__ flagp, int useA, int useB) {
  __shared__ __align__(16) bf16 As[128 * 32];
  __shared__ __align__(16) bf16 Bs[128 * 32];
  const bool f32g = (*flagp != 0);
  const bool fA = useA && f32g;
  const bool fB = useB && f32g;
  const int tid  = threadIdx.x;
  const int lane = tid & 63;
  const int wv   = tid >> 6;
  const int wm   = (wv & 1) << 6;
  const int wn   = (wv >> 1) << 6;
  const long bm  = (long)blockIdx.y * 128;
  const long bn  = (long)blockIdx.x * 128;

  f32x4 acc[4][4] = {};

  for (int k0 = 0; k0 < K; k0 += 32) {
#pragma unroll
    for (int it = 0; it < 2; ++it) {
      int e   = (it * 256 + tid) * 8;
      int row = e >> 5;
      int col = e & 31;
      long offA = (bm + row) * (long)K + (k0 + col);
      long offB = (bn + row) * (long)K + (k0 + col);
      if (fA) {
        const float* g = (const float*)Araw + offA;
        f32x4 u0 = *(const f32x4*)g, u1 = *(const f32x4*)(g + 4);
        bf16x8 bv;
#pragma unroll
        for (int j = 0; j < 4; ++j) { bv[j] = (bf16)u0[j]; bv[4 + j] = (bf16)u1[j]; }
        *(bf16x8*)&As[e] = bv;
      } else {
        const bf16* g = (const bf16*)Araw + offA;
        __builtin_amdgcn_global_load_lds(
            (__attribute__((address_space(1))) const void*)g,
            (__attribute__((address_space(3))) void*)&As[e], 16, 0, 0);
      }
      if (fB) {
        const float* g = (const float*)Braw + offB;
        f32x4 u0 = *(const f32x4*)g, u1 = *(const f32x4*)(g + 4);
        bf16x8 bv;
#pragma unroll
        for (int j = 0; j < 4; ++j) { bv[j] = (bf16)u0[j]; bv[4 + j] = (bf16)u1[j]; }
        *(bf16x8*)&Bs[e] = bv;
      } else {
        const bf16* g = (const bf16*)Braw + offB;
        __builtin_amdgcn_global_load_lds(
            (__attribute__((address_space(1))) const void*)g,
            (__attribute__((address_space(3))) void*)&Bs[e], 16, 0, 0);
      }
    }
    __syncthreads();

    const bf16x8* As8 = (const bf16x8*)As;
    const bf16x8* Bs8 = (const bf16x8*)Bs;
    const int r = lane & 15, q = lane >> 4;
    bf16x8 af[4], bfr[4];
#pragma unroll
    for (int i = 0; i < 4; ++i) af[i]  = As8[(wm + i * 16 + r) * 4 + q];
#pragma unroll
    for (int j = 0; j < 4; ++j) bfr[j] = Bs8[(wn + j * 16 + r) * 4 + q];
#pragma unroll
    for (int i = 0; i < 4; ++i)
#pragma unroll
      for (int j = 0; j < 4; ++j)
        acc[i][j] = __builtin_amdgcn_mfma_f32_16x16x32_bf16(af[i], bfr[j], acc[i][j], 0, 0, 0);
    __syncthreads();
  }

  const int r = lane & 15, q = lane >> 4;
#pragma unroll
  for (int i = 0; i < 4; ++i)
#pragma unroll
    for (int j = 0; j < 4; ++j) {
      long row = bm + wm + i * 16 + q * 4;
      long col = bn + wn + j * 16 + r;
#pragma unroll
      for (int rr = 0; rr < 4; ++rr) {
        if constexpr (F32OUT) ((float*)Cv)[(row + rr) * N + col] = acc[i][j][rr];
        else                  ((bf16*)Cv)[(row + rr) * N + col] = (bf16)acc[i][j][rr];
      }
    }
}

// ---------------------------------------------------------------- GEMM body (bf16-only, fused)
__device__ void gemm_body_bf16(char* smemc, const bf16* __restrict__ A,
                               const bf16* __restrict__ B, bf16* __restrict__ C,
                               int N, int K, int bx, int by, int tid) {
  bf16* As = (bf16*)smemc;             // 8 KiB
  bf16* Bs = (bf16*)(smemc + 8192);    // 8 KiB
  const int lane = tid & 63;
  const int wv = tid >> 6, wm = (wv & 1) << 6, wn = (wv >> 1) << 6;
  const long bm = (long)by * 128, bn = (long)bx * 128;
  f32x4 acc[4][4] = {};
  for (int k0 = 0; k0 < K; k0 += 32) {
#pragma unroll
    for (int it = 0; it < 2; ++it) {
      int e = (it * 256 + tid) * 8;
      int row = e >> 5, col = e & 31;
      const bf16* gA = A + (bm + row) * (long)K + k0 + col;
      const bf16* gB = B + (bn + row) * (long)K + k0 + col;
      __builtin_amdgcn_global_load_lds(
          (__attribute__((address_space(1))) const void*)gA,
          (__attribute__((address_space(3))) void*)&As[e], 16, 0, 0);
      __builtin_amdgcn_global_load_lds(
          (__attribute__((address_space(1))) const void*)gB,
          (__attribute__((address_space(3))) void*)&Bs[e], 16, 0, 0);
    }
    __syncthreads();
    const bf16x8* As8 = (const bf16x8*)As;
    const bf16x8* Bs8 = (const bf16x8*)Bs;
    const int r = lane & 15, q = lane >> 4;
    bf16x8 af[4], bfr[4];
#pragma unroll
    for (int i = 0; i < 4; ++i) af[i]  = As8[(wm + i * 16 + r) * 4 + q];
#pragma unroll
    for (int j = 0; j < 4; ++j) bfr[j] = Bs8[(wn + j * 16 + r) * 4 + q];
#pragma unroll
    for (int i = 0; i < 4; ++i)
#pragma unroll
      for (int j = 0; j < 4; ++j)
        acc[i][j] = __builtin_amdgcn_mfma_f32_16x16x32_bf16(af[i], bfr[j], acc[i][j], 0, 0, 0);
    __syncthreads();
  }
  const int r = lane & 15, q = lane >> 4;
#pragma unroll
  for (int i = 0; i < 4; ++i)
#pragma unroll
    for (int j = 0; j < 4; ++j) {
      long row = bm + wm + i * 16 + q * 4;
      long col = bn + wn + j * 16 + r;
#pragma unroll
      for (int rr = 0; rr < 4; ++rr)
        C[(row + rr) * (long)N + col] = (bf16)acc[i][j][rr];
    }
}

// ---------------------------------------------------------------- a/b proj -> exp(g), beta
__global__ __launch_bounds__(256)
void proj_ab(const void* __restrict__ hsr, const void* __restrict__ War,
             const void* __restrict__ Wbr, const void* __restrict__ A_logr,
             const void* __restrict__ dtbr,
             float* __restrict__ eg, float* __restrict__ bet,
             const unsigned* __restrict__ flagp) {
  const bool f32g = (*flagp != 0);
  const int s = blockIdx.x;
  const int t = threadIdx.x;
  const int o = t & 31;
  const int part = t >> 5;
  const int h = o & 15;
  const int kbeg = part * 256;
  float a0 = 0.f, a1 = 0.f;
  if (f32g) {
    const f32x4* x4 = (const f32x4*)((const float*)hsr + (long)s * HIDDEN + kbeg);
    const f32x4* w4 = (const f32x4*)((const float*)((o < 16) ? War : Wbr) + (long)h * HIDDEN + kbeg);
#pragma unroll 8
    for (int k4 = 0; k4 < 64; ++k4) {
      f32x4 xv = x4[k4], wv = w4[k4];
      a0 += xv[0] * wv[0] + xv[1] * wv[1];
      a1 += xv[2] * wv[2] + xv[3] * wv[3];
    }
  } else {
    const bf16x8* x8 = (const bf16x8*)((const bf16*)hsr + (long)s * HIDDEN + kbeg);
    const bf16x8* w8 = (const bf16x8*)((const bf16*)((o < 16) ? War : Wbr) + (long)h * HIDDEN + kbeg);
#pragma unroll 8
    for (int k8 = 0; k8 < 32; ++k8) {
      bf16x8 xv = x8[k8], wv = w8[k8];
#pragma unroll
      for (int j = 0; j < 4; ++j) a0 += (float)xv[j] * (float)wv[j];
#pragma unroll
      for (int j = 4; j < 8; ++j) a1 += (float)xv[j] * (float)wv[j];
    }
  }
  __shared__ float red[256];
  red[t] = a0 + a1;
  __syncthreads();
  if (t < 32) {
    float a = 0.f;
#pragma unroll
    for (int p = 0; p < 8; ++p) a += red[t + p * 32];
    const int hh = t & 15;
    if (t < 16) {
      float alog = f32g ? ((const float*)A_logr)[hh] : b2f(((const u16*)A_logr)[hh]);
      float dtb  = f32g ? ((const float*)dtbr)[hh]   : b2f(((const u16*)dtbr)[hh]);
      float xx = a + dtb;
      float sp = fmaxf(xx, 0.f) + log1pf(__expf(-fabsf(xx)));   // stable softplus
      eg[(long)s * NH + hh] = __expf(-__expf(alog) * sp);
    } else {
      bet[(long)s * NH + hh] = sigmoidf_(a);
    }
  }
}

// ---------------------------------------------------------------- conv + SiLU + l2norm
__global__ __launch_bounds__(256)
void conv_norm(const bf16* __restrict__ mixed, const void* __restrict__ convwr,
               bf16* __restrict__ qbuf, bf16* __restrict__ kbuf, bf16* __restrict__ vbuf,
               const unsigned* __restrict__ flagp) {
  const bool f32g = (*flagp != 0);
  const int s = blockIdx.x;
  const int c = blockIdx.y * 256 + threadIdx.x;
  float w0, w1, w2, w3;
  if (f32g) {
    const float* wp = (const float*)convwr + (long)c * 4;
    w0 = wp[0]; w1 = wp[1]; w2 = wp[2]; w3 = wp[3];
  } else {
    const u16* wp = (const u16*)convwr + (long)c * 4;
    w0 = b2f(wp[0]); w1 = b2f(wp[1]); w2 = b2f(wp[2]); w3 = b2f(wp[3]);
  }
  float acc = w3 * (float)mixed[(long)s * CONV_DIM + c];
  if (s >= 1) acc += w2 * (float)mixed[(long)(s - 1) * CONV_DIM + c];
  if (s >= 2) acc += w1 * (float)mixed[(long)(s - 2) * CONV_DIM + c];
  if (s >= 3) acc += w0 * (float)mixed[(long)(s - 3) * CONV_DIM + c];
  float y = acc * sigmoidf_(acc);  // SiLU
  if (c < 2 * KEY_DIM) {
    float ss = y * y;
    ss += __shfl_xor(ss, 1);  ss += __shfl_xor(ss, 2);  ss += __shfl_xor(ss, 4);
    ss += __shfl_xor(ss, 8);  ss += __shfl_xor(ss, 16); ss += __shfl_xor(ss, 32);
    float scale = rsqrtf(ss + 1e-6f);
    if (c < KEY_DIM) scale *= 0.125f;
    y *= scale;
  }
  if (c < KEY_DIM)            qbuf[(long)s * KEY_DIM + c] = (bf16)y;
  else if (c < 2 * KEY_DIM)   kbuf[(long)s * KEY_DIM + (c - KEY_DIM)] = (bf16)y;
  else                        vbuf[(long)s * VAL_DIM + (c - 2 * KEY_DIM)] = (bf16)y;
}

// ---------------------------------------------------------------- DPP 16-lane sum
template<int CTRL>
__device__ __forceinline__ float dpp_add(float x) {
  int y = __builtin_amdgcn_update_dpp(0, __float_as_int(x), CTRL, 0xF, 0xF, true);
  return x + __int_as_float(y);
}
__device__ __forceinline__ float dpp_sum16(float x) {
  x = dpp_add<0xB1>(x);   // quad_perm xor1
  x = dpp_add<0x4E>(x);   // quad_perm xor2
  x = dpp_add<0x141>(x);  // row_half_mirror (xor4)
  x = dpp_add<0x140>(x);  // row_mirror (xor8)
  return x;
}

// ---------------------------------------------------------------- fused scan / z-gemm / wout-cvt
__global__ __launch_bounds__(256, 2)
void fused_scan(const bf16* __restrict__ qbuf, const bf16* __restrict__ kbuf,
                const bf16* __restrict__ vbuf, const float* __restrict__ eg,
                const float* __restrict__ bet, bf16* __restrict__ core,
                const bf16* __restrict__ hsb, const bf16* __restrict__ wzb,
                bf16* __restrict__ zbuf, const void* __restrict__ woutr,
                bf16* __restrict__ woutb, const unsigned* __restrict__ flagp,
                int nScan, int nGemm) {
  __shared__ __align__(16) char smem[16384];
  const int t = threadIdx.x;
  const int b = blockIdx.x;

  if (b < nScan) {
    // ------------- scan: column (h,v) per 16 lanes; lane L holds S[L*4..L*4+4)[v].
    // k/q/v in LDS via global_load_lds DMA, double-buffered 16-step tiles. -------------
    const int h  = b >> 3;
    const int vg = (b & 7) * 16;
    const int g  = t >> 4;
    const int L  = t & 15;
    bf16*  kqs = (bf16*)smem;               // [2][2048] elems: kt(16x64)+qt(16x64) per buf
    bf16*  vts = (bf16*)(smem + 8192);      // [2][256] elems: 16x16
    float* ets = (float*)(smem + 9216);     // [2][16]
    float* bts = (float*)(smem + 9344);     // [2][16]

#define STAGE(buf, s0)                                                          \
    {                                                                           \
      int byte = t * 16;                                                        \
      const bf16* src;                                                          \
      if (byte < 2048) {                                                        \
        int row = byte >> 7, el = (byte & 127) >> 1;                            \
        src = kbuf + (long)((s0) + row) * KEY_DIM + h * DKv + el;               \
      } else {                                                                  \
        int b2 = byte - 2048;                                                   \
        int row = b2 >> 7, el = (b2 & 127) >> 1;                                \
        src = qbuf + (long)((s0) + row) * KEY_DIM + h * DKv + el;               \
      }                                                                         \
      __builtin_amdgcn_global_load_lds(                                         \
          (__attribute__((address_space(1))) const void*)src,                   \
          (__attribute__((address_space(3))) void*)(smem + (buf) * 4096 + byte),\
          16, 0, 0);                                                            \
      if (t < 32) {                                                             \
        int row = t >> 1, el = (t & 1) * 8;                                     \
        const bf16* vsrc = vbuf + (long)((s0) + row) * VAL_DIM + h * DVv + vg + el; \
        __builtin_amdgcn_global_load_lds(                                       \
            (__attribute__((address_space(1))) const void*)vsrc,                \
            (__attribute__((address_space(3))) void*)(smem + 8192 + (buf) * 512 + t * 16), \
            16, 0, 0);                                                          \
      }                                                                         \
    }

    float er = 0.f, br = 0.f;
    if (t < 16)      er = eg[(long)t * NH + h];
    else if (t < 32) br = bet[(long)(t - 16) * NH + h];
    STAGE(0, 0);
    if (t < 16)      ets[t] = er;
    else if (t < 32) bts[t - 16] = br;
    __syncthreads();

    float S0 = 0.f, S1 = 0.f, S2 = 0.f, S3 = 0.f;
    for (int tile = 0; tile < 128; ++tile) {
      const int buf = tile & 1, nb = buf ^ 1;
      if (tile < 127) {
        STAGE(nb, (tile + 1) * 16);
        if (t < 16)      er = eg[(long)((tile + 1) * 16 + t) * NH + h];
        else if (t < 32) br = bet[(long)((tile + 1) * 16 + (t - 16)) * NH + h];
      }
      const bf16*  ktb = kqs + buf * 2048;
      const bf16*  qtb = ktb + 1024;
      const bf16*  vtb = vts + buf * 256;
      const float* etb = ets + buf * 16;
      const float* btb = bts + buf * 16;
      const long sbase = (long)tile * 16;
#pragma unroll
      for (int s = 0; s < 16; ++s) {
        bf16x4 kk = *(const bf16x4*)(ktb + s * 64 + L * 4);
        bf16x4 qq = *(const bf16x4*)(qtb + s * 64 + L * 4);
        float vv = (float)vtb[s * 16 + g];
        float ee = etb[s], bb = btb[s];
        float ebt = ee * bb, vbt = vv * bb;
        float k0 = (float)kk[0], k1 = (float)kk[1], k2 = (float)kk[2], k3 = (float)kk[3];
        float D0 = S0 * ee, D1 = S1 * ee, D2 = S2 * ee, D3 = S3 * ee;
        float p = (k0 * S0 + k1 * S1) + (k2 * S2 + k3 * S3);
        p = dpp_sum16(p);
        float delta = vbt - ebt * p;
        S0 = fmaf(k0, delta, D0); S1 = fmaf(k1, delta, D1);
        S2 = fmaf(k2, delta, D2); S3 = fmaf(k3, delta, D3);
        float q0 = (float)qq[0], q1 = (float)qq[1], q2 = (float)qq[2], q3 = (float)qq[3];
        float o = (q0 * S0 + q1 * S1) + (q2 * S2 + q3 * S3);
        o = dpp_sum16(o);
        if (L == 0) core[(sbase + s) * VAL_DIM + h * DVv + vg + g] = (bf16)o;
      }
      if (tile < 127) {
        if (t < 16)      ets[nb * 16 + t] = er;
        else if (t < 32) bts[nb * 16 + (t - 16)] = br;
      }
      __syncthreads();  // drains this wave's tile+1 DMA (aged a full tile) + LDS writes
    }
#undef STAGE
  } else if (b < nScan + nGemm) {
    // ------------- z-gemm: zbuf = hsb @ wzb^T (256 tiles) -------------
    int gb = b - nScan;
    gemm_body_bf16(smem, hsb, wzb, zbuf, VAL_DIM, HIDDEN, gb & 15, gb >> 4, t);
  } else {
    // ------------- wout cvt (f32 -> bf16, 8 elems/thread) -------------
    long i = ((long)(b - nScan - nGemm) * 256 + t) * 8;
    if (i < (long)HIDDEN * VAL_DIM) {
      if (*flagp) {
        const f32x4* s = (const f32x4*)((const float*)woutr + i);
        f32x4 a = s[0], c = s[1];
        bf16x8 o;
#pragma unroll
        for (int j = 0; j < 4; ++j) { o[j] = (bf16)a[j]; o[4 + j] = (bf16)c[j]; }
        *(bf16x8*)(woutb + i) = o;
      } else {
        *(bf16x8*)(woutb + i) = *(const bf16x8*)((const bf16*)woutr + i);
      }
    }
  }
}

// ---------------------------------------------------------------- RMSNorm + SiLU(z) gate
__global__ __launch_bounds__(256)
void gate_norm(const bf16* __restrict__ core, const bf16* __restrict__ zb,
               const void* __restrict__ normwr, bf16* __restrict__ gated,
               const unsigned* __restrict__ flagp) {
  const bool f32g = (*flagp != 0);
  const int s  = blockIdx.x;
  const int t  = threadIdx.x;
  const int h  = t >> 4;
  const int li = t & 15;
  const long base = (long)s * VAL_DIM + h * DVv + li * 8;
  bf16x8 c8 = *(const bf16x8*)(core + base);
  bf16x8 z8 = *(const bf16x8*)(zb + base);
  float x[8], z[8], nw[8];
  float ss = 0.f;
#pragma unroll
  for (int j = 0; j < 8; ++j) { x[j] = (float)c8[j]; z[j] = (float)z8[j]; ss += x[j] * x[j]; }
  if (f32g) {
    const float* np_ = (const float*)normwr + li * 8;
#pragma unroll
    for (int j = 0; j < 8; ++j) nw[j] = np_[j];
  } else {
    const u16* np_ = (const u16*)normwr + li * 8;
#pragma unroll
    for (int j = 0; j < 8; ++j) nw[j] = b2f(np_[j]);
  }
  ss += __shfl_xor(ss, 1); ss += __shfl_xor(ss, 2);
  ss += __shfl_xor(ss, 4); ss += __shfl_xor(ss, 8);
  float scale = rsqrtf(ss * (1.f / 128.f) + 1e-6f);
#pragma unroll
  for (int j = 0; j < 8; ++j) {
    float y = x[j] * scale * nw[j];
    y *= z[j] * sigmoidf_(z[j]);
    gated[base + j] = (bf16)y;
  }
}

// ---------------------------------------------------------------- launcher
extern "C" void kernel_launch(void* const* d_in, const int* in_sizes, int n_in,
                              void* d_out, int out_size, void* d_ws, size_t ws_size,
                              hipStream_t stream) {
  char* ws = (char*)d_ws;
  const bool big = ws_size >= ((48u << 20) + (512u << 10));

  if (big) {
    // Big layout (peak 48.26 MiB):
    //   [0,8M)   hsb bf16
    //   [8,24M)  wqkvb bf16 (gemm1) -> after: wzb @8M (4M), zbuf @16M (8M)
    //   [24,40M) mixed bf16 (gemm1->conv) -> after conv: core @24M (8M), woutb @32M (8M)
    //   [40,44M) qbuf  [44,48M) kbuf (conv->scan) -> after scan: gated @40M (8M)
    //   [48M..)  eg (128K) | beta (128K) | flag
    //   d_out: vbuf bf16 (first 8M, conv->scan); gemm3 overwrites all 16M as f32.
    bf16* hsb   = (bf16*)ws;
    bf16* wqkvb = (bf16*)(ws + (8u << 20));
    bf16* wzb   = (bf16*)(ws + (8u << 20));
    bf16* zbuf  = (bf16*)(ws + (16u << 20));
    bf16* mixed = (bf16*)(ws + (24u << 20));
    bf16* corep = (bf16*)(ws + (24u << 20));
    bf16* woutb = (bf16*)(ws + (32u << 20));
    bf16* qbuf  = (bf16*)(ws + (40u << 20));
    bf16* kbuf  = (bf16*)(ws + (44u << 20));
    bf16* gated = (bf16*)(ws + (40u << 20));
    float* egp  = (float*)(ws + (48u << 20));
    float* betp = (float*)(ws + (48u << 20) + (128u << 10));
    unsigned* flagp = (unsigned*)(ws + (48u << 20) + (256u << 10));
    bf16* vbuf  = (bf16*)d_out;

    detect_dtype<<<1, 64, 0, stream>>>((const u16*)d_in[0], flagp);
    proj_ab<<<SEQ, 256, 0, stream>>>(d_in[0], d_in[2], d_in[3], d_in[6], d_in[7], egp, betp, flagp);
    cvt_bf16<<<(SEQ * HIDDEN) / 2048, 256, 0, stream>>>(d_in[0], hsb, (long)SEQ * HIDDEN, flagp);
    cvt_bf16<<<(CONV_DIM * HIDDEN) / 2048, 256, 0, stream>>>(d_in[1], wqkvb, (long)CONV_DIM * HIDDEN, flagp);
    gemm_nt<false><<<dim3(CONV_DIM / 128, SEQ / 128), 256, 0, stream>>>(hsb, wqkvb, mixed, CONV_DIM, HIDDEN, flagp, 0, 0);
    cvt_bf16<<<(VAL_DIM * HIDDEN) / 2048, 256, 0, stream>>>(d_in[4], wzb, (long)VAL_DIM * HIDDEN, flagp);
    conv_norm<<<dim3(SEQ, CONV_DIM / 256), 256, 0, stream>>>(mixed, d_in[5], qbuf, kbuf, vbuf, flagp);
    fused_scan<<<128 + 256 + 2048, 256, 0, stream>>>(qbuf, kbuf, vbuf, egp, betp, corep,
                                                     hsb, wzb, zbuf, d_in[9], woutb, flagp,
                                                     128, 256);
    gate_norm<<<SEQ, 256, 0, stream>>>(corep, zbuf, d_in[8], gated, flagp);
    gemm_nt<true><<<dim3(HIDDEN / 128, SEQ / 128), 256, 0, stream>>>(gated, woutb, d_out, HIDDEN, VAL_DIM, flagp, 0, 0);
  } else {
    // Fallback layout (peak 24.26 MiB): r6-style staging GEMMs; scan-only fused kernel.
    bf16* mixed = (bf16*)ws;
    bf16* qbuf  = (bf16*)(ws + (16u << 20));
    bf16* kbuf  = (bf16*)(ws + (20u << 20));
    bf16* zbuf  = (bf16*)ws;
    bf16* corep = (bf16*)(ws + (8u << 20));
    bf16* gated = (bf16*)(ws + (16u << 20));
    float* egp  = (float*)(ws + (24u << 20));
    float* betp = (float*)(ws + (24u << 20) + (128u << 10));
    unsigned* flagp = (unsigned*)(ws + (24u << 20) + (256u << 10));
    bf16* vbuf  = (bf16*)d_out;

    detect_dtype<<<1, 64, 0, stream>>>((const u16*)d_in[0], flagp);
    proj_ab<<<SEQ, 256, 0, stream>>>(d_in[0], d_in[2], d_in[3], d_in[6], d_in[7], egp, betp, flagp);
    gemm_nt<false><<<dim3(CONV_DIM / 128, SEQ / 128), 256, 0, stream>>>(d_in[0], d_in[1], mixed, CONV_DIM, HIDDEN, flagp, 1, 1);
    conv_norm<<<dim3(SEQ, CONV_DIM / 256), 256, 0, stream>>>(mixed, d_in[5], qbuf, kbuf, vbuf, flagp);
    gemm_nt<false><<<dim3(VAL_DIM / 128, SEQ / 128), 256, 0, stream>>>(d_in[0], d_in[4], zbuf, VAL_DIM, HIDDEN, flagp, 1, 1);
    fused_scan<<<128, 256, 0, stream>>>(qbuf, kbuf, vbuf, egp, betp, corep,
                                        nullptr, nullptr, nullptr, nullptr, nullptr, flagp,
                                        128, 0);
    gate_norm<<<SEQ, 256, 0, stream>>>(corep, zbuf, d_in[8], gated, flagp);
    gemm_nt<true><<<dim3(HIDDEN / 128, SEQ / 128), 256, 0, stream>>>(gated, d_in[9], d_out, HIDDEN, VAL_DIM, flagp, 0, 1);
  }
}

// Round 10
// 673.138 us; speedup vs baseline: 2.1647x; 1.1128x over previous
//
#include <hip/hip_runtime.h>
#include <stdint.h>

// LinearAttention (gated delta rule), S=2048, HID=2048, H=16, DK=64, DV=128, conv K=4.
// Established: inputs f32 (runtime-detected), output f32. r9: 749 us, fused scan 400 us.
// r10: scan v5 — keep r9's LDS DMA staging, add a 2-deep register software pipeline
// over the per-step ds_reads (k/q/v/e/b): consume slot s&1, immediately reload it with
// step s+2. Takes the ~120-cyc ds_read latency off the serial chain (r7/r8/r9 all
// plateaued at ~400-470 cyc/step because per-step LDS/global reads sat on the chain).
//
// Pipeline: detect -> proj_ab -> cvt(hs,wqkv) -> gemm(QKV) -> cvt(wz) -> conv
//           -> FUSED[scan | z-gemm | wout-cvt] -> gate -> gemm(out, f32) -> d_out

#define SEQ 2048
#define HIDDEN 2048
#define NH 16
#define DKv 64
#define DVv 128
#define KEY_DIM 1024
#define VAL_DIM 2048
#define CONV_DIM 4096

typedef __bf16 bf16;
typedef unsigned short u16;
typedef __attribute__((ext_vector_type(8))) __bf16 bf16x8;
typedef __attribute__((ext_vector_type(4))) __bf16 bf16x4;
typedef __attribute__((ext_vector_type(4))) float f32x4;

__device__ __forceinline__ float b2f(u16 u) {
  union { unsigned int i; float f; } c; c.i = ((unsigned int)u) << 16; return c.f;
}
__device__ __forceinline__ float sigmoidf_(float x) { return 1.0f / (1.0f + __expf(-x)); }

// ---------------------------------------------------------------- dtype detector
__global__ void detect_dtype(const u16* __restrict__ p, unsigned* __restrict__ flag) {
  int lane = threadIdx.x;  // 64 threads
  int cnt = 0;
  for (int w = lane; w < 2048; w += 64) {
    unsigned e = (p[2 * w] >> 7) & 0xFF;
    if (e < 64) cnt++;
  }
  cnt += __shfl_xor(cnt, 1);  cnt += __shfl_xor(cnt, 2);  cnt += __shfl_xor(cnt, 4);
  cnt += __shfl_xor(cnt, 8);  cnt += __shfl_xor(cnt, 16); cnt += __shfl_xor(cnt, 32);
  if (lane == 0) *flag = (cnt > 64) ? 1u : 0u;   // 1 = inputs are f32
}

// ---------------------------------------------------------------- f32 -> bf16 convert
__global__ __launch_bounds__(256)
void cvt_bf16(const void* __restrict__ src, bf16* __restrict__ dst, long n,
              const unsigned* __restrict__ flagp) {
  long i = ((long)blockIdx.x * 256 + threadIdx.x) * 8;
  if (i >= n) return;
  if (*flagp) {
    const f32x4* s = (const f32x4*)((const float*)src + i);
    f32x4 a = s[0], b = s[1];
    bf16x8 o;
#pragma unroll
    for (int j = 0; j < 4; ++j) { o[j] = (bf16)a[j]; o[4 + j] = (bf16)b[j]; }
    *(bf16x8*)(dst + i) = o;
  } else {
    *(bf16x8*)(dst + i) = *(const bf16x8*)((const bf16*)src + i);
  }
}

// ---------------------------------------------------------------- GEMM (NT) standalone
template<bool F32OUT>
__global__ __launch_bounds__(256, 2)
void gemm_nt(const void* __restrict__ Araw, const void* __restrict__ Braw,
             void* __restrict__ Cv, int N, int K,
             const unsigned* __restrict__ flagp, int useA, int useB) {
  __shared__ __align__(16) bf16 As[128 * 32];
  __shared__ __align__(16) bf16 Bs[128 * 32];
  const bool f32g = (*flagp != 0);
  const bool fA = useA && f32g;
  const bool fB = useB && f32g;
  const int tid  = threadIdx.x;
  const int lane = tid & 63;
  const int wv   = tid >> 6;
  const int wm   = (wv & 1) << 6;
  const int wn   = (wv >> 1) << 6;
  const long bm  = (long)blockIdx.y * 128;
  const long bn  = (long)blockIdx.x * 128;

  f32x4 acc[4][4] = {};

  for (int k0 = 0; k0 < K; k0 += 32) {
#pragma unroll
    for (int it = 0; it < 2; ++it) {
      int e   = (it * 256 + tid) * 8;
      int row = e >> 5;
      int col = e & 31;
      long offA = (bm + row) * (long)K + (k0 + col);
      long offB = (bn + row) * (long)K + (k0 + col);
      if (fA) {
        const float* g = (const float*)Araw + offA;
        f32x4 u0 = *(const f32x4*)g, u1 = *(const f32x4*)(g + 4);
        bf16x8 bv;
#pragma unroll
        for (int j = 0; j < 4; ++j) { bv[j] = (bf16)u0[j]; bv[4 + j] = (bf16)u1[j]; }
        *(bf16x8*)&As[e] = bv;
      } else {
        const bf16* g = (const bf16*)Araw + offA;
        __builtin_amdgcn_global_load_lds(
            (__attribute__((address_space(1))) const void*)g,
            (__attribute__((address_space(3))) void*)&As[e], 16, 0, 0);
      }
      if (fB) {
        const float* g = (const float*)Braw + offB;
        f32x4 u0 = *(const f32x4*)g, u1 = *(const f32x4*)(g + 4);
        bf16x8 bv;
#pragma unroll
        for (int j = 0; j < 4; ++j) { bv[j] = (bf16)u0[j]; bv[4 + j] = (bf16)u1[j]; }
        *(bf16x8*)&Bs[e] = bv;
      } else {
        const bf16* g = (const bf16*)Braw + offB;
        __builtin_amdgcn_global_load_lds(
            (__attribute__((address_space(1))) const void*)g,
            (__attribute__((address_space(3))) void*)&Bs[e], 16, 0, 0);
      }
    }
    __syncthreads();

    const bf16x8* As8 = (const bf16x8*)As;
    const bf16x8* Bs8 = (const bf16x8*)Bs;
    const int r = lane & 15, q = lane >> 4;
    bf16x8 af[4], bfr[4];
#pragma unroll
    for (int i = 0; i < 4; ++i) af[i]  = As8[(wm + i * 16 + r) * 4 + q];
#pragma unroll
    for (int j = 0; j < 4; ++j) bfr[j] = Bs8[(wn + j * 16 + r) * 4 + q];
#pragma unroll
    for (int i = 0; i < 4; ++i)
#pragma unroll
      for (int j = 0; j < 4; ++j)
        acc[i][j] = __builtin_amdgcn_mfma_f32_16x16x32_bf16(af[i], bfr[j], acc[i][j], 0, 0, 0);
    __syncthreads();
  }

  const int r = lane & 15, q = lane >> 4;
#pragma unroll
  for (int i = 0; i < 4; ++i)
#pragma unroll
    for (int j = 0; j < 4; ++j) {
      long row = bm + wm + i * 16 + q * 4;
      long col = bn + wn + j * 16 + r;
#pragma unroll
      for (int rr = 0; rr < 4; ++rr) {
        if constexpr (F32OUT) ((float*)Cv)[(row + rr) * N + col] = acc[i][j][rr];
        else                  ((bf16*)Cv)[(row + rr) * N + col] = (bf16)acc[i][j][rr];
      }
    }
}

// ---------------------------------------------------------------- GEMM body (bf16-only, fused)
__device__ void gemm_body_bf16(char* smemc, const bf16* __restrict__ A,
                               const bf16* __restrict__ B, bf16* __restrict__ C,
                               int N, int K, int bx, int by, int tid) {
  bf16* As = (bf16*)smemc;             // 8 KiB
  bf16* Bs = (bf16*)(smemc + 8192);    // 8 KiB
  const int lane = tid & 63;
  const int wv = tid >> 6, wm = (wv & 1) << 6, wn = (wv >> 1) << 6;
  const long bm = (long)by * 128, bn = (long)bx * 128;
  f32x4 acc[4][4] = {};
  for (int k0 = 0; k0 < K; k0 += 32) {
#pragma unroll
    for (int it = 0; it < 2; ++it) {
      int e = (it * 256 + tid) * 8;
      int row = e >> 5, col = e & 31;
      const bf16* gA = A + (bm + row) * (long)K + k0 + col;
      const bf16* gB = B + (bn + row) * (long)K + k0 + col;
      __builtin_amdgcn_global_load_lds(
          (__attribute__((address_space(1))) const void*)gA,
          (__attribute__((address_space(3))) void*)&As[e], 16, 0, 0);
      __builtin_amdgcn_global_load_lds(
          (__attribute__((address_space(1))) const void*)gB,
          (__attribute__((address_space(3))) void*)&Bs[e], 16, 0, 0);
    }
    __syncthreads();
    const bf16x8* As8 = (const bf16x8*)As;
    const bf16x8* Bs8 = (const bf16x8*)Bs;
    const int r = lane & 15, q = lane >> 4;
    bf16x8 af[4], bfr[4];
#pragma unroll
    for (int i = 0; i < 4; ++i) af[i]  = As8[(wm + i * 16 + r) * 4 + q];
#pragma unroll
    for (int j = 0; j < 4; ++j) bfr[j] = Bs8[(wn + j * 16 + r) * 4 + q];
#pragma unroll
    for (int i = 0; i < 4; ++i)
#pragma unroll
      for (int j = 0; j < 4; ++j)
        acc[i][j] = __builtin_amdgcn_mfma_f32_16x16x32_bf16(af[i], bfr[j], acc[i][j], 0, 0, 0);
    __syncthreads();
  }
  const int r = lane & 15, q = lane >> 4;
#pragma unroll
  for (int i = 0; i < 4; ++i)
#pragma unroll
    for (int j = 0; j < 4; ++j) {
      long row = bm + wm + i * 16 + q * 4;
      long col = bn + wn + j * 16 + r;
#pragma unroll
      for (int rr = 0; rr < 4; ++rr)
        C[(row + rr) * (long)N + col] = (bf16)acc[i][j][rr];
    }
}

// ---------------------------------------------------------------- a/b proj -> exp(g), beta
__global__ __launch_bounds__(256)
void proj_ab(const void* __restrict__ hsr, const void* __restrict__ War,
             const void* __restrict__ Wbr, const void* __restrict__ A_logr,
             const void* __restrict__ dtbr,
             float* __restrict__ eg, float* __restrict__ bet,
             const unsigned* __restrict__ flagp) {
  const bool f32g = (*flagp != 0);
  const int s = blockIdx.x;
  const int t = threadIdx.x;
  const int o = t & 31;
  const int part = t >> 5;
  const int h = o & 15;
  const int kbeg = part * 256;
  float a0 = 0.f, a1 = 0.f;
  if (f32g) {
    const f32x4* x4 = (const f32x4*)((const float*)hsr + (long)s * HIDDEN + kbeg);
    const f32x4* w4 = (const f32x4*)((const float*)((o < 16) ? War : Wbr) + (long)h * HIDDEN + kbeg);
#pragma unroll 8
    for (int k4 = 0; k4 < 64; ++k4) {
      f32x4 xv = x4[k4], wv = w4[k4];
      a0 += xv[0] * wv[0] + xv[1] * wv[1];
      a1 += xv[2] * wv[2] + xv[3] * wv[3];
    }
  } else {
    const bf16x8* x8 = (const bf16x8*)((const bf16*)hsr + (long)s * HIDDEN + kbeg);
    const bf16x8* w8 = (const bf16x8*)((const bf16*)((o < 16) ? War : Wbr) + (long)h * HIDDEN + kbeg);
#pragma unroll 8
    for (int k8 = 0; k8 < 32; ++k8) {
      bf16x8 xv = x8[k8], wv = w8[k8];
#pragma unroll
      for (int j = 0; j < 4; ++j) a0 += (float)xv[j] * (float)wv[j];
#pragma unroll
      for (int j = 4; j < 8; ++j) a1 += (float)xv[j] * (float)wv[j];
    }
  }
  __shared__ float red[256];
  red[t] = a0 + a1;
  __syncthreads();
  if (t < 32) {
    float a = 0.f;
#pragma unroll
    for (int p = 0; p < 8; ++p) a += red[t + p * 32];
    const int hh = t & 15;
    if (t < 16) {
      float alog = f32g ? ((const float*)A_logr)[hh] : b2f(((const u16*)A_logr)[hh]);
      float dtb  = f32g ? ((const float*)dtbr)[hh]   : b2f(((const u16*)dtbr)[hh]);
      float xx = a + dtb;
      float sp = fmaxf(xx, 0.f) + log1pf(__expf(-fabsf(xx)));   // stable softplus
      eg[(long)s * NH + hh] = __expf(-__expf(alog) * sp);
    } else {
      bet[(long)s * NH + hh] = sigmoidf_(a);
    }
  }
}

// ---------------------------------------------------------------- conv + SiLU + l2norm
__global__ __launch_bounds__(256)
void conv_norm(const bf16* __restrict__ mixed, const void* __restrict__ convwr,
               bf16* __restrict__ qbuf, bf16* __restrict__ kbuf, bf16* __restrict__ vbuf,
               const unsigned* __restrict__ flagp) {
  const bool f32g = (*flagp != 0);
  const int s = blockIdx.x;
  const int c = blockIdx.y * 256 + threadIdx.x;
  float w0, w1, w2, w3;
  if (f32g) {
    const float* wp = (const float*)convwr + (long)c * 4;
    w0 = wp[0]; w1 = wp[1]; w2 = wp[2]; w3 = wp[3];
  } else {
    const u16* wp = (const u16*)convwr + (long)c * 4;
    w0 = b2f(wp[0]); w1 = b2f(wp[1]); w2 = b2f(wp[2]); w3 = b2f(wp[3]);
  }
  float acc = w3 * (float)mixed[(long)s * CONV_DIM + c];
  if (s >= 1) acc += w2 * (float)mixed[(long)(s - 1) * CONV_DIM + c];
  if (s >= 2) acc += w1 * (float)mixed[(long)(s - 2) * CONV_DIM + c];
  if (s >= 3) acc += w0 * (float)mixed[(long)(s - 3) * CONV_DIM + c];
  float y = acc * sigmoidf_(acc);  // SiLU
  if (c < 2 * KEY_DIM) {
    float ss = y * y;
    ss += __shfl_xor(ss, 1);  ss += __shfl_xor(ss, 2);  ss += __shfl_xor(ss, 4);
    ss += __shfl_xor(ss, 8);  ss += __shfl_xor(ss, 16); ss += __shfl_xor(ss, 32);
    float scale = rsqrtf(ss + 1e-6f);
    if (c < KEY_DIM) scale *= 0.125f;
    y *= scale;
  }
  if (c < KEY_DIM)            qbuf[(long)s * KEY_DIM + c] = (bf16)y;
  else if (c < 2 * KEY_DIM)   kbuf[(long)s * KEY_DIM + (c - KEY_DIM)] = (bf16)y;
  else                        vbuf[(long)s * VAL_DIM + (c - 2 * KEY_DIM)] = (bf16)y;
}

// ---------------------------------------------------------------- DPP 16-lane sum
template<int CTRL>
__device__ __forceinline__ float dpp_add(float x) {
  int y = __builtin_amdgcn_update_dpp(0, __float_as_int(x), CTRL, 0xF, 0xF, true);
  return x + __int_as_float(y);
}
__device__ __forceinline__ float dpp_sum16(float x) {
  x = dpp_add<0xB1>(x);   // quad_perm xor1
  x = dpp_add<0x4E>(x);   // quad_perm xor2
  x = dpp_add<0x141>(x);  // row_half_mirror (xor4)
  x = dpp_add<0x140>(x);  // row_mirror (xor8)
  return x;
}

// ---------------------------------------------------------------- fused scan / z-gemm / wout-cvt
__global__ __launch_bounds__(256, 2)
void fused_scan(const bf16* __restrict__ qbuf, const bf16* __restrict__ kbuf,
                const bf16* __restrict__ vbuf, const float* __restrict__ eg,
                const float* __restrict__ bet, bf16* __restrict__ core,
                const bf16* __restrict__ hsb, const bf16* __restrict__ wzb,
                bf16* __restrict__ zbuf, const void* __restrict__ woutr,
                bf16* __restrict__ woutb, const unsigned* __restrict__ flagp,
                int nScan, int nGemm) {
  __shared__ __align__(16) char smem[16384];
  const int t = threadIdx.x;
  const int b = blockIdx.x;

  if (b < nScan) {
    // ------------- scan: column (h,v) per 16 lanes; lane L holds S[L*4..L*4+4)[v].
    // LDS DMA staging (16-step tiles, double-buffered) + 2-deep register pipeline
    // over per-step ds_reads so ds latency stays off the serial chain. -------------
    const int h  = b >> 3;
    const int vg = (b & 7) * 16;
    const int g  = t >> 4;
    const int L  = t & 15;
    bf16*  kqs = (bf16*)smem;               // [2][2048] elems: kt(16x64)+qt(16x64) per buf
    bf16*  vts = (bf16*)(smem + 8192);      // [2][256] elems: 16x16
    float* ets = (float*)(smem + 9216);     // [2][16]
    float* bts = (float*)(smem + 9344);     // [2][16]

#define STAGE(buf, s0)                                                          \
    {                                                                           \
      int byte = t * 16;                                                        \
      const bf16* src;                                                          \
      if (byte < 2048) {                                                        \
        int row = byte >> 7, el = (byte & 127) >> 1;                            \
        src = kbuf + (long)((s0) + row) * KEY_DIM + h * DKv + el;               \
      } else {                                                                  \
        int b2 = byte - 2048;                                                   \
        int row = b2 >> 7, el = (b2 & 127) >> 1;                                \
        src = qbuf + (long)((s0) + row) * KEY_DIM + h * DKv + el;               \
      }                                                                         \
      __builtin_amdgcn_global_load_lds(                                         \
          (__attribute__((address_space(1))) const void*)src,                   \
          (__attribute__((address_space(3))) void*)(smem + (buf) * 4096 + byte),\
          16, 0, 0);                                                            \
      if (t < 32) {                                                             \
        int row = t >> 1, el = (t & 1) * 8;                                     \
        const bf16* vsrc = vbuf + (long)((s0) + row) * VAL_DIM + h * DVv + vg + el; \
        __builtin_amdgcn_global_load_lds(                                       \
            (__attribute__((address_space(1))) const void*)vsrc,                \
            (__attribute__((address_space(3))) void*)(smem + 8192 + (buf) * 512 + t * 16), \
            16, 0, 0);                                                          \
      }                                                                         \
    }

    float er = 0.f, br = 0.f;
    if (t < 16)      er = eg[(long)t * NH + h];
    else if (t < 32) br = bet[(long)(t - 16) * NH + h];
    STAGE(0, 0);
    if (t < 16)      ets[t] = er;
    else if (t < 32) bts[t - 16] = br;
    __syncthreads();

    float S0 = 0.f, S1 = 0.f, S2 = 0.f, S3 = 0.f;
    for (int tile = 0; tile < 128; ++tile) {
      const int buf = tile & 1, nb = buf ^ 1;
      if (tile < 127) {
        STAGE(nb, (tile + 1) * 16);
        if (t < 16)      er = eg[(long)((tile + 1) * 16 + t) * NH + h];
        else if (t < 32) br = bet[(long)((tile + 1) * 16 + (t - 16)) * NH + h];
      }
      const bf16*  ktb = kqs + buf * 2048;
      const bf16*  qtb = ktb + 1024;
      const bf16*  vtb = vts + buf * 256;
      const float* etb = ets + buf * 16;
      const float* btb = bts + buf * 16;
      const long sbase = (long)tile * 16;

      // 2-deep register pipeline over the 16 steps of this tile.
      bf16x4 kR[2], qR[2];
      float  vR[2], eR[2], bR[2];
      kR[0] = *(const bf16x4*)(ktb + 0 * 64 + L * 4);
      qR[0] = *(const bf16x4*)(qtb + 0 * 64 + L * 4);
      vR[0] = (float)vtb[0 * 16 + g];  eR[0] = etb[0];  bR[0] = btb[0];
      kR[1] = *(const bf16x4*)(ktb + 1 * 64 + L * 4);
      qR[1] = *(const bf16x4*)(qtb + 1 * 64 + L * 4);
      vR[1] = (float)vtb[1 * 16 + g];  eR[1] = etb[1];  bR[1] = btb[1];
#pragma unroll
      for (int s = 0; s < 16; ++s) {
        const int sl = s & 1;
        bf16x4 kk = kR[sl], qq = qR[sl];
        float vv = vR[sl], ee = eR[sl], bb = bR[sl];
        if (s < 14) {                       // reload slot with step s+2 (in-tile)
          const int s2 = s + 2;
          kR[sl] = *(const bf16x4*)(ktb + s2 * 64 + L * 4);
          qR[sl] = *(const bf16x4*)(qtb + s2 * 64 + L * 4);
          vR[sl] = (float)vtb[s2 * 16 + g];
          eR[sl] = etb[s2];  bR[sl] = btb[s2];
        }
        float ebt = ee * bb, vbt = vv * bb;
        float k0 = (float)kk[0], k1 = (float)kk[1], k2 = (float)kk[2], k3 = (float)kk[3];
        float D0 = S0 * ee, D1 = S1 * ee, D2 = S2 * ee, D3 = S3 * ee;
        float p = (k0 * S0 + k1 * S1) + (k2 * S2 + k3 * S3);
        p = dpp_sum16(p);
        float delta = vbt - ebt * p;
        S0 = fmaf(k0, delta, D0); S1 = fmaf(k1, delta, D1);
        S2 = fmaf(k2, delta, D2); S3 = fmaf(k3, delta, D3);
        float q0 = (float)qq[0], q1 = (float)qq[1], q2 = (float)qq[2], q3 = (float)qq[3];
        float o = (q0 * S0 + q1 * S1) + (q2 * S2 + q3 * S3);
        o = dpp_sum16(o);
        if (L == 0) core[(sbase + s) * VAL_DIM + h * DVv + vg + g] = (bf16)o;
      }
      if (tile < 127) {
        if (t < 16)      ets[nb * 16 + t] = er;
        else if (t < 32) bts[nb * 16 + (t - 16)] = br;
      }
      __syncthreads();  // drains this wave's tile+1 DMA + LDS e/b writes
    }
#undef STAGE
  } else if (b < nScan + nGemm) {
    // ------------- z-gemm: zbuf = hsb @ wzb^T (256 tiles) -------------
    int gb = b - nScan;
    gemm_body_bf16(smem, hsb, wzb, zbuf, VAL_DIM, HIDDEN, gb & 15, gb >> 4, t);
  } else {
    // ------------- wout cvt (f32 -> bf16, 8 elems/thread) -------------
    long i = ((long)(b - nScan - nGemm) * 256 + t) * 8;
    if (i < (long)HIDDEN * VAL_DIM) {
      if (*flagp) {
        const f32x4* s = (const f32x4*)((const float*)woutr + i);
        f32x4 a = s[0], c = s[1];
        bf16x8 o;
#pragma unroll
        for (int j = 0; j < 4; ++j) { o[j] = (bf16)a[j]; o[4 + j] = (bf16)c[j]; }
        *(bf16x8*)(woutb + i) = o;
      } else {
        *(bf16x8*)(woutb + i) = *(const bf16x8*)((const bf16*)woutr + i);
      }
    }
  }
}

// ---------------------------------------------------------------- RMSNorm + SiLU(z) gate
__global__ __launch_bounds__(256)
void gate_norm(const bf16* __restrict__ core, const bf16* __restrict__ zb,
               const void* __restrict__ normwr, bf16* __restrict__ gated,
               const unsigned* __restrict__ flagp) {
  const bool f32g = (*flagp != 0);
  const int s  = blockIdx.x;
  const int t  = threadIdx.x;
  const int h  = t >> 4;
  const int li = t & 15;
  const long base = (long)s * VAL_DIM + h * DVv + li * 8;
  bf16x8 c8 = *(const bf16x8*)(core + base);
  bf16x8 z8 = *(const bf16x8*)(zb + base);
  float x[8], z[8], nw[8];
  float ss = 0.f;
#pragma unroll
  for (int j = 0; j < 8; ++j) { x[j] = (float)c8[j]; z[j] = (float)z8[j]; ss += x[j] * x[j]; }
  if (f32g) {
    const float* np_ = (const float*)normwr + li * 8;
#pragma unroll
    for (int j = 0; j < 8; ++j) nw[j] = np_[j];
  } else {
    const u16* np_ = (const u16*)normwr + li * 8;
#pragma unroll
    for (int j = 0; j < 8; ++j) nw[j] = b2f(np_[j]);
  }
  ss += __shfl_xor(ss, 1); ss += __shfl_xor(ss, 2);
  ss += __shfl_xor(ss, 4); ss += __shfl_xor(ss, 8);
  float scale = rsqrtf(ss * (1.f / 128.f) + 1e-6f);
#pragma unroll
  for (int j = 0; j < 8; ++j) {
    float y = x[j] * scale * nw[j];
    y *= z[j] * sigmoidf_(z[j]);
    gated[base + j] = (bf16)y;
  }
}

// ---------------------------------------------------------------- launcher
extern "C" void kernel_launch(void* const* d_in, const int* in_sizes, int n_in,
                              void* d_out, int out_size, void* d_ws, size_t ws_size,
                              hipStream_t stream) {
  char* ws = (char*)d_ws;
  const bool big = ws_size >= ((48u << 20) + (512u << 10));

  if (big) {
    // Big layout (peak 48.26 MiB):
    //   [0,8M)   hsb bf16
    //   [8,24M)  wqkvb bf16 (gemm1) -> after: wzb @8M (4M), zbuf @16M (8M)
    //   [24,40M) mixed bf16 (gemm1->conv) -> after conv: core @24M (8M), woutb @32M (8M)
    //   [40,44M) qbuf  [44,48M) kbuf (conv->scan) -> after scan: gated @40M (8M)
    //   [48M..)  eg (128K) | beta (128K) | flag
    //   d_out: vbuf bf16 (first 8M, conv->scan); gemm3 overwrites all 16M as f32.
    bf16* hsb   = (bf16*)ws;
    bf16* wqkvb = (bf16*)(ws + (8u << 20));
    bf16* wzb   = (bf16*)(ws + (8u << 20));
    bf16* zbuf  = (bf16*)(ws + (16u << 20));
    bf16* mixed = (bf16*)(ws + (24u << 20));
    bf16* corep = (bf16*)(ws + (24u << 20));
    bf16* woutb = (bf16*)(ws + (32u << 20));
    bf16* qbuf  = (bf16*)(ws + (40u << 20));
    bf16* kbuf  = (bf16*)(ws + (44u << 20));
    bf16* gated = (bf16*)(ws + (40u << 20));
    float* egp  = (float*)(ws + (48u << 20));
    float* betp = (float*)(ws + (48u << 20) + (128u << 10));
    unsigned* flagp = (unsigned*)(ws + (48u << 20) + (256u << 10));
    bf16* vbuf  = (bf16*)d_out;

    detect_dtype<<<1, 64, 0, stream>>>((const u16*)d_in[0], flagp);
    proj_ab<<<SEQ, 256, 0, stream>>>(d_in[0], d_in[2], d_in[3], d_in[6], d_in[7], egp, betp, flagp);
    cvt_bf16<<<(SEQ * HIDDEN) / 2048, 256, 0, stream>>>(d_in[0], hsb, (long)SEQ * HIDDEN, flagp);
    cvt_bf16<<<(CONV_DIM * HIDDEN) / 2048, 256, 0, stream>>>(d_in[1], wqkvb, (long)CONV_DIM * HIDDEN, flagp);
    gemm_nt<false><<<dim3(CONV_DIM / 128, SEQ / 128), 256, 0, stream>>>(hsb, wqkvb, mixed, CONV_DIM, HIDDEN, flagp, 0, 0);
    cvt_bf16<<<(VAL_DIM * HIDDEN) / 2048, 256, 0, stream>>>(d_in[4], wzb, (long)VAL_DIM * HIDDEN, flagp);
    conv_norm<<<dim3(SEQ, CONV_DIM / 256), 256, 0, stream>>>(mixed, d_in[5], qbuf, kbuf, vbuf, flagp);
    fused_scan<<<128 + 256 + 2048, 256, 0, stream>>>(qbuf, kbuf, vbuf, egp, betp, corep,
                                                     hsb, wzb, zbuf, d_in[9], woutb, flagp,
                                                     128, 256);
    gate_norm<<<SEQ, 256, 0, stream>>>(corep, zbuf, d_in[8], gated, flagp);
    gemm_nt<true><<<dim3(HIDDEN / 128, SEQ / 128), 256, 0, stream>>>(gated, woutb, d_out, HIDDEN, VAL_DIM, flagp, 0, 0);
  } else {
    // Fallback layout (peak 24.26 MiB): r6-style staging GEMMs; scan-only fused kernel.
    bf16* mixed = (bf16*)ws;
    bf16* qbuf  = (bf16*)(ws + (16u << 20));
    bf16* kbuf  = (bf16*)(ws + (20u << 20));
    bf16* zbuf  = (bf16*)ws;
    bf16* corep = (bf16*)(ws + (8u << 20));
    bf16* gated = (bf16*)(ws + (16u << 20));
    float* egp  = (float*)(ws + (24u << 20));
    float* betp = (float*)(ws + (24u << 20) + (128u << 10));
    unsigned* flagp = (unsigned*)(ws + (24u << 20) + (256u << 10));
    bf16* vbuf  = (bf16*)d_out;

    detect_dtype<<<1, 64, 0, stream>>>((const u16*)d_in[0], flagp);
    proj_ab<<<SEQ, 256, 0, stream>>>(d_in[0], d_in[2], d_in[3], d_in[6], d_in[7], egp, betp, flagp);
    gemm_nt<false><<<dim3(CONV_DIM / 128, SEQ / 128), 256, 0, stream>>>(d_in[0], d_in[1], mixed, CONV_DIM, HIDDEN, flagp, 1, 1);
    conv_norm<<<dim3(SEQ, CONV_DIM / 256), 256, 0, stream>>>(mixed, d_in[5], qbuf, kbuf, vbuf, flagp);
    gemm_nt<false><<<dim3(VAL_DIM / 128, SEQ / 128), 256, 0, stream>>>(d_in[0], d_in[4], zbuf, VAL_DIM, HIDDEN, flagp, 1, 1);
    fused_scan<<<128, 256, 0, stream>>>(qbuf, kbuf, vbuf, egp, betp, corep,
                                        nullptr, nullptr, nullptr, nullptr, nullptr, flagp,
                                        128, 0);
    gate_norm<<<SEQ, 256, 0, stream>>>(corep, zbuf, d_in[8], gated, flagp);
    gemm_nt<true><<<dim3(HIDDEN / 128, SEQ / 128), 256, 0, stream>>>(gated, d_in[9], d_out, HIDDEN, VAL_DIM, flagp, 0, 1);
  }
}